// Round 8
// baseline (70.886 us; speedup 1.0000x reference)
//
#include <hip/hip_runtime.h>
#include <math.h>

// Problem constants
#define B       200
#define V       40
#define FIN     16
#define H       128
#define NSW     12
#define NE      40
#define M       52      // NE + NSW
#define MLP_HID 1024
#define OUTD    104     // M + V + NSW
#define MLP_IN  6656    // (NSW + V) * H
#define ZDIM    144
#define ZCDIM   132
#define NCH     13      // MLP split-K chunks
#define X1LD    136     // x1 LDS row stride (shorts)
#define MAXD    16      // max adjacency degree

typedef __attribute__((ext_vector_type(8))) short bf16x8;
typedef __attribute__((ext_vector_type(4))) float f32x4;

__device__ __forceinline__ float sigmoidf(float x) {
    return 1.0f / (1.0f + expf(-x));
}
__device__ __forceinline__ unsigned short f2b(float x) {  // fp32 -> bf16 RNE
    unsigned int u = __float_as_uint(x);
    u += 0x7fffu + ((u >> 16) & 1u);
    return (unsigned short)(u >> 16);
}
__device__ __forceinline__ float b2f(unsigned short s) {
    return __uint_as_float(((unsigned int)s) << 16);
}

// ---------------- weight prep + accumulator init ----------------
// bx<8:    {WU0,WV0,WB0,WC0} -> W0t[col][k] 512x32 (k>=16 zero)
// 8<=bx<48:  {WU1,WV1,WB1,WC1,WA1} -> Wt640[col][f] 640x128
// 48<=bx<80: hiddenF = 0           (256x1024 f32)
// 80<=bx<84: oF[b][col] = b2[col] (col<104) else 0   (256x128 f32)
__global__ __launch_bounds__(256) void k_prep(
        const float* __restrict__ WU0, const float* __restrict__ WV0,
        const float* __restrict__ WB0, const float* __restrict__ WC0,
        const float* __restrict__ WU1, const float* __restrict__ WV1,
        const float* __restrict__ WB1, const float* __restrict__ WC1,
        const float* __restrict__ WA1, const float* __restrict__ b2,
        unsigned short* __restrict__ W0t, unsigned short* __restrict__ Wt640,
        float* __restrict__ hiddenF, float* __restrict__ oF) {
    int bx = blockIdx.x, tid = threadIdx.x;
    if (bx < 8) {
        int o0 = bx * 2048 + tid * 8;
#pragma unroll
        for (int i = 0; i < 8; ++i) {
            int o = o0 + i; int col = o >> 5, k = o & 31;
            int m = col >> 7, hh = col & 127;
            const float* Ws = (m == 0) ? WU0 : (m == 1) ? WV0 : (m == 2) ? WB0 : WC0;
            W0t[o] = (k < FIN) ? f2b(Ws[k * H + hh]) : (unsigned short)0;
        }
    } else if (bx < 48) {
        int o0 = (bx - 8) * 2048 + tid * 8;
#pragma unroll
        for (int i = 0; i < 8; ++i) {
            int o = o0 + i; int col = o >> 7, f = o & 127;
            int m = col >> 7, hh = col & 127;
            const float* Ws = (m == 0) ? WU1 : (m == 1) ? WV1 : (m == 2) ? WB1
                            : (m == 3) ? WC1 : WA1;
            Wt640[o] = f2b(Ws[f * H + hh]);
        }
    } else if (bx < 80) {
        float4 z = {0.f, 0.f, 0.f, 0.f};
        float4* dst = (float4*)(hiddenF + (size_t)(bx - 48) * 8192) + tid;
#pragma unroll
        for (int i = 0; i < 8; ++i) dst[i * 256] = z;
    } else {
        int base = (bx - 80) * 8192 + tid * 32;
#pragma unroll
        for (int i = 0; i < 32; ++i) {
            int o = base + i; int col = o & 127;
            oF[o] = (col < OUTD) ? b2[col] : 0.f;
        }
    }
}

// ---------------- fully fused GNN (MFMA proj, adjacency-list message passing) ----------------
// one block per batch, 512 threads (8 waves), ~78 KB LDS
__global__ __launch_bounds__(512) void k_gnn(const float* __restrict__ x,
        const int* __restrict__ ei, const int* __restrict__ si,
        const float* __restrict__ embed, const float* __restrict__ WA0,
        const unsigned short* __restrict__ W0t,
        const unsigned short* __restrict__ Wt640,
        unsigned short* __restrict__ Abf) {
    int b = blockIdx.x, tid = threadIdx.x;
    __shared__ unsigned short xb[48 * 40];      // x bf16, rows 40-47 & k 16-31 zero
    __shared__ unsigned short uvbc[V * 512];    // [row][m*128+h] (L0, then L1)
    __shared__ unsigned short x1l[64 * X1LD];   // rows 0-39 x1; 48-59 relu(e0); rest 0
    __shared__ float gL[NSW * H];               // gates (L0, then L1)
    __shared__ float sA1l[NSW * H];
    __shared__ int   nbr[V][MAXD];
    __shared__ int   deg[V];

    int h = tid & 127, sub = tid >> 7;
    int lane = tid & 63, wv = tid >> 6;
    int lr = lane & 15, lk = lane >> 4;
    int n0w = wv * 64;

    // ---- phase 1: load x (bf16, padded), zero deg + x1l pad rows ----
    for (int o = tid; o < 48 * 32; o += 512) {
        int r = o >> 5, k = o & 31;
        float v = (r < V && k < FIN) ? x[(size_t)b * V * FIN + r * FIN + k] : 0.f;
        xb[r * 40 + k] = f2b(v);
    }
    if (tid < V) deg[tid] = 0;
    for (int o = tid; o < 12 * 128; o += 512) {
        int rr = o >> 7;
        int row = (rr < 8) ? 40 + rr : 60 + (rr - 8);
        x1l[row * X1LD + (o & 127)] = 0;
    }
    __syncthreads();

    // ---- phase 2: adjacency build + proj0 MFMA -> uvbc(L0) ----
    if (tid < NE) {
        int i = ei[tid], j = ei[NE + tid];
        int p = atomicAdd(&deg[i], 1); if (p < MAXD) nbr[i][p] = j;
        int q = atomicAdd(&deg[j], 1); if (q < MAXD) nbr[j][q] = i;
    } else if (tid < NE + NSW) {
        int k = tid - NE;
        int i = si[k], j = si[NSW + k];
        int p = atomicAdd(&deg[i], 1); if (p < MAXD) nbr[i][p] = j | ((k + 1) << 8);
    }
    {
        f32x4 acc[3][4];
#pragma unroll
        for (int rf = 0; rf < 3; ++rf)
#pragma unroll
            for (int cf = 0; cf < 4; ++cf) acc[rf][cf] = (f32x4){0.f, 0.f, 0.f, 0.f};
        int kseg = lk * 8;
        bf16x8 a0 = *(const bf16x8*)&xb[lr * 40 + kseg];
        bf16x8 a1 = *(const bf16x8*)&xb[(16 + lr) * 40 + kseg];
        bf16x8 a2 = *(const bf16x8*)&xb[(32 + lr) * 40 + kseg];
#pragma unroll
        for (int cf = 0; cf < 4; ++cf) {
            bf16x8 bf = *(const bf16x8*)&W0t[(n0w + cf * 16 + lr) * 32 + kseg];
            acc[0][cf] = __builtin_amdgcn_mfma_f32_16x16x32_bf16(a0, bf, acc[0][cf], 0, 0, 0);
            acc[1][cf] = __builtin_amdgcn_mfma_f32_16x16x32_bf16(a1, bf, acc[1][cf], 0, 0, 0);
            acc[2][cf] = __builtin_amdgcn_mfma_f32_16x16x32_bf16(a2, bf, acc[2][cf], 0, 0, 0);
        }
#pragma unroll
        for (int rf = 0; rf < 3; ++rf)
#pragma unroll
            for (int cf = 0; cf < 4; ++cf)
#pragma unroll
                for (int r = 0; r < 4; ++r) {
                    int row = rf * 16 + lk * 4 + r;
                    if (row < V) uvbc[row * 512 + n0w + cf * 16 + lr] = f2b(acc[rf][cf][r]);
                }
    }
    __syncthreads();

    // ---- phase 3: layer-0 gates -> gL; relu(e0) -> x1l rows 48..59 ----
    {
        float sA0 = 0.f;
#pragma unroll
        for (int f = 0; f < FIN; ++f) sA0 += embed[FIN + f] * WA0[f * H + h];
        for (int k = sub; k < NSW; k += 4) {
            int i = si[k], j = si[NSW + k];
            float e0 = sA0 + b2f(uvbc[i * 512 + 256 + h]) + b2f(uvbc[j * 512 + 384 + h]);
            gL[k * H + h] = sigmoidf(e0);
            x1l[(48 + k) * X1LD + h] = f2b(fmaxf(e0, 0.f));
        }
    }
    __syncthreads();

    // ---- phase 4: x1 via adjacency -> x1l rows 0..39 ----
    for (int i = sub * 10; i < sub * 10 + 10; ++i) {
        float acc = b2f(uvbc[i * 512 + h]);          // Ux
        int d = deg[i]; if (d > MAXD) d = MAXD;
        for (int p = 0; p < d; ++p) {
            int ent = nbr[i][p];
            float vv = b2f(uvbc[(ent & 255) * 512 + 128 + h]);   // Vx[j]
            int g = ent >> 8;
            if (g) vv *= gL[(g - 1) * H + h];
            acc += vv;
        }
        x1l[i * X1LD + h] = f2b(fmaxf(acc, 0.f));    // layer 0: no residual
    }
    __syncthreads();

    // ---- phase 5: proj1 + sA1 MFMA -> uvbc(L1), sA1l ----
    {
        f32x4 acc[3][4], accs = (f32x4){0.f, 0.f, 0.f, 0.f};
#pragma unroll
        for (int rf = 0; rf < 3; ++rf)
#pragma unroll
            for (int cf = 0; cf < 4; ++cf) acc[rf][cf] = (f32x4){0.f, 0.f, 0.f, 0.f};
#pragma unroll
        for (int kk = 0; kk < 4; ++kk) {
            int kseg = kk * 32 + lk * 8;
            bf16x8 a0 = *(const bf16x8*)&x1l[lr * X1LD + kseg];
            bf16x8 a1 = *(const bf16x8*)&x1l[(16 + lr) * X1LD + kseg];
            bf16x8 a2 = *(const bf16x8*)&x1l[(32 + lr) * X1LD + kseg];
            bf16x8 as = *(const bf16x8*)&x1l[(48 + lr) * X1LD + kseg];
#pragma unroll
            for (int cf = 0; cf < 4; ++cf) {
                bf16x8 bf = *(const bf16x8*)&Wt640[(size_t)(n0w + cf * 16 + lr) * H + kseg];
                acc[0][cf] = __builtin_amdgcn_mfma_f32_16x16x32_bf16(a0, bf, acc[0][cf], 0, 0, 0);
                acc[1][cf] = __builtin_amdgcn_mfma_f32_16x16x32_bf16(a1, bf, acc[1][cf], 0, 0, 0);
                acc[2][cf] = __builtin_amdgcn_mfma_f32_16x16x32_bf16(a2, bf, acc[2][cf], 0, 0, 0);
            }
            bf16x8 bs = *(const bf16x8*)&Wt640[(size_t)(512 + wv * 16 + lr) * H + kseg];
            accs = __builtin_amdgcn_mfma_f32_16x16x32_bf16(as, bs, accs, 0, 0, 0);
        }
#pragma unroll
        for (int rf = 0; rf < 3; ++rf)
#pragma unroll
            for (int cf = 0; cf < 4; ++cf)
#pragma unroll
                for (int r = 0; r < 4; ++r) {
                    int row = rf * 16 + lk * 4 + r;
                    if (row < V) uvbc[row * 512 + n0w + cf * 16 + lr] = f2b(acc[rf][cf][r]);
                }
#pragma unroll
        for (int r = 0; r < 4; ++r) {
            int sr = lk * 4 + r;
            if (sr < NSW) sA1l[sr * H + wv * 16 + lr] = accs[r];
        }
    }
    __syncthreads();

    // ---- phase 6: layer-1 gates -> gL; s2 switch rows -> Abf ----
    for (int k = sub; k < NSW; k += 4) {
        int i = si[k], j = si[NSW + k];
        float e1 = sA1l[k * H + h] + b2f(uvbc[i * 512 + 256 + h]) + b2f(uvbc[j * 512 + 384 + h]);
        gL[k * H + h] = sigmoidf(e1);
        float s1 = b2f(x1l[(48 + k) * X1LD + h]);
        Abf[(size_t)b * MLP_IN + k * H + h] = f2b(s1 + fmaxf(e1, 0.f));
    }
    __syncthreads();

    // ---- phase 7: x2 via adjacency (residual) -> Abf ----
    for (int i = sub * 10; i < sub * 10 + 10; ++i) {
        float acc = b2f(uvbc[i * 512 + h]);
        int d = deg[i]; if (d > MAXD) d = MAXD;
        for (int p = 0; p < d; ++p) {
            int ent = nbr[i][p];
            float vv = b2f(uvbc[(ent & 255) * 512 + 128 + h]);
            int g = ent >> 8;
            if (g) vv *= gL[(g - 1) * H + h];
            acc += vv;
        }
        float x2 = b2f(x1l[i * X1LD + h]) + fmaxf(acc, 0.f);
        Abf[(size_t)b * MLP_IN + NSW * H + i * H + h] = f2b(x2);
    }
}

// ---------------- MLP GEMM: fused W1 transpose+convert, atomic split-K epilogue ----------------
// hiddenF[m][n] += Abf[m][k-chunk] @ W1[k-chunk][n]; grid(8,4,NCH), block 256
// block tile 64 rows x 128 cols; wave tile 32x64 (2x4 fragments, 8 MFMA/k-step)
__global__ __launch_bounds__(256) void k_mlp(const unsigned short* __restrict__ A,
        const float* __restrict__ W1, float* __restrict__ hiddenF) {
    const int NK = 16;
    int tid = threadIdx.x;
    int lane = tid & 63, wvv = tid >> 6;
    int wr = (wvv >> 1) * 32, wc = (wvv & 1) * 64;
    int n0 = blockIdx.x * 128, m0 = blockIdx.y * 64;
    int kbase = blockIdx.z * NK * 32;

    __shared__ __align__(16) unsigned short a_lds[64 * 40];
    __shared__ __align__(16) unsigned short b_lds[128 * 40];

    f32x4 acc[2][4];
#pragma unroll
    for (int r = 0; r < 2; ++r)
#pragma unroll
        for (int c = 0; c < 4; ++c) acc[r][c] = (f32x4){0.f, 0.f, 0.f, 0.f};

    // A staging: thread -> (srow, 8 consecutive k)
    int srow = tid >> 2, sseg = tid & 3;
    const int4* gA = (const int4*)(A + (size_t)(m0 + srow) * MLP_IN + kbase + sseg * 8);
    int lwsA = srow * 40 + sseg * 8;

    // B staging: thread -> (bcol, 16 consecutive k); W1 row-major [k][n]
    int bcol = tid & 127, bkg = tid >> 7;
    const float* gW = W1 + (size_t)(kbase + bkg * 16) * MLP_HID + n0 + bcol;
    int lwsB = bcol * 40 + bkg * 16;

    int a_off = (wr + (lane & 15)) * 40 + (lane >> 4) * 8;
    int b_off = (wc + (lane & 15)) * 40 + (lane >> 4) * 8;

    int4 ra = gA[0];
    float rf[16];
#pragma unroll
    for (int i = 0; i < 16; ++i) rf[i] = gW[(size_t)i * MLP_HID];

    for (int kk = 0; kk < NK; ++kk) {
        *(int4*)&a_lds[lwsA] = ra;
        union { unsigned short us[16]; int4 v[2]; } pk;
#pragma unroll
        for (int i = 0; i < 16; ++i) pk.us[i] = f2b(rf[i]);
        *(int4*)&b_lds[lwsB] = pk.v[0];
        *(int4*)&b_lds[lwsB + 8] = pk.v[1];
        __syncthreads();
        if (kk + 1 < NK) {
            ra = gA[(kk + 1) * 4];
            const float* g2 = gW + (size_t)(kk + 1) * 32 * MLP_HID;
#pragma unroll
            for (int i = 0; i < 16; ++i) rf[i] = g2[(size_t)i * MLP_HID];
        }
        bf16x8 a0 = *(const bf16x8*)&a_lds[a_off];
        bf16x8 a1 = *(const bf16x8*)&a_lds[a_off + 16 * 40];
#pragma unroll
        for (int c = 0; c < 4; ++c) {
            bf16x8 bf = *(const bf16x8*)&b_lds[b_off + c * 16 * 40];
            acc[0][c] = __builtin_amdgcn_mfma_f32_16x16x32_bf16(a0, bf, acc[0][c], 0, 0, 0);
            acc[1][c] = __builtin_amdgcn_mfma_f32_16x16x32_bf16(a1, bf, acc[1][c], 0, 0, 0);
        }
        __syncthreads();
    }

    int crow = (lane >> 4) * 4, ccol = lane & 15;
#pragma unroll
    for (int r = 0; r < 2; ++r)
#pragma unroll
        for (int c = 0; c < 4; ++c) {
            int row = m0 + wr + r * 16 + crow;
            int col = n0 + wc + c * 16 + ccol;
#pragma unroll
            for (int e = 0; e < 4; ++e)
                atomicAdd(&hiddenF[(size_t)(row + e) * MLP_HID + col], acc[r][c][e]);
        }
}

// ---------------- head GEMM: A = relu(hiddenF+b1) packed, B = W2 transposed, atomic oF ----------------
// grid(1,4,4): block tile 64 rows x 128 cols, K chunk 256 (nk=8)
__global__ __launch_bounds__(256) void k_head(const float* __restrict__ hiddenF,
        const float* __restrict__ b1, const float* __restrict__ W2,
        float* __restrict__ oF) {
    const int NK = 8;
    int tid = threadIdx.x;
    int lane = tid & 63, wvv = tid >> 6;
    int wr = (wvv >> 1) * 32, wc = (wvv & 1) * 64;
    int m0 = blockIdx.y * 64;
    int kbase = blockIdx.z * NK * 32;

    __shared__ __align__(16) unsigned short a_lds[64 * 40];
    __shared__ __align__(16) unsigned short b_lds[128 * 40];

    f32x4 acc[2][4];
#pragma unroll
    for (int r = 0; r < 2; ++r)
#pragma unroll
        for (int c = 0; c < 4; ++c) acc[r][c] = (f32x4){0.f, 0.f, 0.f, 0.f};

    int srow = tid >> 2, sseg = tid & 3;
    const float* gH = hiddenF + (size_t)(m0 + srow) * MLP_HID + kbase + sseg * 8;
    const float* gb = b1 + kbase + sseg * 8;
    int lwsA = srow * 40 + sseg * 8;

    int bcol = tid & 127, bkg = tid >> 7;
    int lwsB = bcol * 40 + bkg * 16;

    int a_off = (wr + (lane & 15)) * 40 + (lane >> 4) * 8;
    int b_off = (wc + (lane & 15)) * 40 + (lane >> 4) * 8;

    for (int kk = 0; kk < NK; ++kk) {
        {
            union { unsigned short us[8]; int4 v; } pa;
#pragma unroll
            for (int i = 0; i < 8; ++i) {
                float v = gH[(size_t)kk * 32 + i] + gb[kk * 32 + i];
                pa.us[i] = f2b(fmaxf(v, 0.f));
            }
            *(int4*)&a_lds[lwsA] = pa.v;
        }
        {
            union { unsigned short us[16]; int4 v[2]; } pb;
            int kb = kbase + kk * 32 + bkg * 16;
#pragma unroll
            for (int i = 0; i < 16; ++i) {
                float v = (bcol < OUTD) ? W2[(size_t)(kb + i) * OUTD + bcol] : 0.f;
                pb.us[i] = f2b(v);
            }
            *(int4*)&b_lds[lwsB] = pb.v[0];
            *(int4*)&b_lds[lwsB + 8] = pb.v[1];
        }
        __syncthreads();
        bf16x8 a0 = *(const bf16x8*)&a_lds[a_off];
        bf16x8 a1 = *(const bf16x8*)&a_lds[a_off + 16 * 40];
#pragma unroll
        for (int c = 0; c < 4; ++c) {
            bf16x8 bf = *(const bf16x8*)&b_lds[b_off + c * 16 * 40];
            acc[0][c] = __builtin_amdgcn_mfma_f32_16x16x32_bf16(a0, bf, acc[0][c], 0, 0, 0);
            acc[1][c] = __builtin_amdgcn_mfma_f32_16x16x32_bf16(a1, bf, acc[1][c], 0, 0, 0);
        }
        __syncthreads();
    }

    int crow = (lane >> 4) * 4, ccol = lane & 15;
#pragma unroll
    for (int r = 0; r < 2; ++r)
#pragma unroll
        for (int c = 0; c < 4; ++c) {
            int row = m0 + wr + r * 16 + crow;
            int col = wc + c * 16 + ccol;
#pragma unroll
            for (int e = 0; e < 4; ++e)
                atomicAdd(&oF[(size_t)(row + e) * 128 + col], acc[r][c][e]);
        }
}

// ---------------- finalize: postprocess ----------------
__global__ __launch_bounds__(128) void k_fin(const float* __restrict__ oF,
        const float* __restrict__ A, const float* __restrict__ x_mod,
        float* __restrict__ outp) {
    int b = blockIdx.x;
    int tid = threadIdx.x;
    __shared__ float o[OUTD];
    __shared__ float gt[M], vv[V], pfc[M], qfc[M];

    if (tid < OUTD) o[tid] = oF[(size_t)b * 128 + tid];
    __syncthreads();

    if (tid < M) {
        float g = (tid < M - NSW) ? 1.0f : sigmoidf(o[M + V + (tid - (M - NSW))]);
        gt[tid] = g;
        pfc[tid] = g * o[tid];
    }
    if (tid < V) vv[tid] = (tid == 0) ? 1.0f : o[M + tid];
    __syncthreads();

    if (tid < M) {
        float acc = 0.f;
        for (int x = 0; x < V; ++x) acc += vv[x] * A[x * M + tid];
        qfc[tid] = gt[tid] * acc;
    }
    __syncthreads();

    float* zb = outp + (size_t)b * ZDIM;
    if (tid < M) zb[tid] = pfc[tid];
    if (tid < V) zb[M + tid] = vv[tid];
    if (tid < M) zb[M + V + tid] = gt[tid];

    float* zcb = outp + (size_t)B * ZDIM + (size_t)b * ZCDIM;
    if (tid < M) zcb[tid] = qfc[tid];
    if (tid < V) {
        float accp = 0.f, accq = 0.f;
        for (int m = 0; m < M; ++m) {
            float a = A[tid * M + m];
            accp += a * pfc[m];
            accq += a * qfc[m];
        }
        zcb[M + tid]     = x_mod[(size_t)(b * V + tid) * FIN + 0] + accp;
        zcb[M + V + tid] = x_mod[(size_t)(b * V + tid) * FIN + 1] + accq;
    }
}

extern "C" void kernel_launch(void* const* d_in, const int* in_sizes, int n_in,
                              void* d_out, int out_size, void* d_ws, size_t ws_size,
                              hipStream_t stream) {
    const float* x_mod = (const float*)d_in[0];
    const int*   ei    = (const int*)d_in[1];
    const int*   si    = (const int*)d_in[2];
    const float* A     = (const float*)d_in[3];
    const float* embed = (const float*)d_in[4];
    const float* WU0   = (const float*)d_in[5];
    const float* WV0   = (const float*)d_in[6];
    const float* WA0   = (const float*)d_in[7];
    const float* WB0   = (const float*)d_in[8];
    const float* WC0   = (const float*)d_in[9];
    const float* WU1   = (const float*)d_in[10];
    const float* WV1   = (const float*)d_in[11];
    const float* WA1   = (const float*)d_in[12];
    const float* WB1   = (const float*)d_in[13];
    const float* WC1   = (const float*)d_in[14];
    const float* W1    = (const float*)d_in[15];
    const float* b1    = (const float*)d_in[16];
    const float* W2    = (const float*)d_in[17];
    const float* b2    = (const float*)d_in[18];
    float* out = (float*)d_out;

    // Workspace layout (byte offsets), ~4.8 MB
    char* ws = (char*)d_ws;
    unsigned short* W0t     = (unsigned short*)(ws + 0);         //    32,768
    unsigned short* Wt640   = (unsigned short*)(ws + 32768);     //   163,840
    unsigned short* Abf     = (unsigned short*)(ws + 196608);    // 3,407,872 (rows >=200 stale-poison, benign)
    float*          hiddenF = (float*)(ws + 3604480);            // 1,048,576
    float*          oF      = (float*)(ws + 4653056);            //   131,072

    // 1. weight prep + zero/init accumulators
    k_prep<<<84, 256, 0, stream>>>(WU0, WV0, WB0, WC0, WU1, WV1, WB1, WC1, WA1, b2,
                                   W0t, Wt640, hiddenF, oF);
    // 2. fully fused GNN (both layers, MFMA projections) -> Abf
    k_gnn<<<B, 512, 0, stream>>>(x_mod, ei, si, embed, WA0, W0t, Wt640, Abf);
    // 3. MLP hidden: (256x6656) @ W1 (f32, transposed on the fly), split-K=13, atomic
    k_mlp<<<dim3(8, 4, NCH), 256, 0, stream>>>(Abf, W1, hiddenF);
    // 4. head GEMM: relu(hiddenF+b1) @ W2 (on-the-fly), split-K=4, atomic into oF
    k_head<<<dim3(1, 4, 4), 256, 0, stream>>>(hiddenF, b1, W2, oF);
    // 5. finalize: graph postprocess
    k_fin<<<B, 128, 0, stream>>>(oF, A, x_mod, out);
}

// Round 9
// 67.938 us; speedup vs baseline: 1.0434x; 1.0434x over previous
//
#include <hip/hip_runtime.h>
#include <math.h>

// Problem constants
#define B       200
#define V       40
#define FIN     16
#define H       128
#define NSW     12
#define NE      40
#define M       52      // NE + NSW
#define MLP_HID 1024
#define OUTD    104     // M + V + NSW
#define MLP_IN  6656    // (NSW + V) * H
#define ZDIM    144
#define ZCDIM   132
#define NCH     13      // MLP split-K chunks
#define X1LD    136     // x1 LDS row stride (shorts)
#define MAXD    16      // max adjacency degree

typedef __attribute__((ext_vector_type(8))) short bf16x8;
typedef __attribute__((ext_vector_type(4))) float f32x4;

__device__ __forceinline__ float sigmoidf(float x) {
    return 1.0f / (1.0f + expf(-x));
}
__device__ __forceinline__ unsigned short f2b(float x) {  // fp32 -> bf16 RNE
    unsigned int u = __float_as_uint(x);
    u += 0x7fffu + ((u >> 16) & 1u);
    return (unsigned short)(u >> 16);
}
__device__ __forceinline__ float b2f(unsigned short s) {
    return __uint_as_float(((unsigned int)s) << 16);
}

// ---------------- weight prep (small mats; W1 handled inside k_mlp) ----------------
// bx<64: W2 (1024x104) -> W2t[col][k] (cols>=104 zero), 128x1024
// 64<=bx<104: {WU1,WV1,WB1,WC1,WA1} -> Wt640[col][f], 640x128
// 104<=bx<112: {WU0,WV0,WB0,WC0} -> W0t[col][k] 512x32, k>=16 zero
__global__ __launch_bounds__(256) void k_prep(
        const float* __restrict__ WU0, const float* __restrict__ WV0,
        const float* __restrict__ WB0, const float* __restrict__ WC0,
        const float* __restrict__ WU1, const float* __restrict__ WV1,
        const float* __restrict__ WB1, const float* __restrict__ WC1,
        const float* __restrict__ WA1, const float* __restrict__ W2,
        unsigned short* __restrict__ W0t, unsigned short* __restrict__ Wt640,
        unsigned short* __restrict__ W2t) {
    int bx = blockIdx.x, tid = threadIdx.x;
    if (bx < 64) {
        int o0 = bx * 2048 + tid * 8;
#pragma unroll
        for (int i = 0; i < 8; ++i) {
            int o = o0 + i; int col = o >> 10, k = o & 1023;
            W2t[o] = (col < OUTD) ? f2b(W2[(size_t)k * OUTD + col]) : (unsigned short)0;
        }
    } else if (bx < 104) {
        int o0 = (bx - 64) * 2048 + tid * 8;
#pragma unroll
        for (int i = 0; i < 8; ++i) {
            int o = o0 + i; int col = o >> 7, f = o & 127;
            int m = col >> 7, hh = col & 127;
            const float* Ws = (m == 0) ? WU1 : (m == 1) ? WV1 : (m == 2) ? WB1
                            : (m == 3) ? WC1 : WA1;
            Wt640[o] = f2b(Ws[f * H + hh]);
        }
    } else {
        int o0 = (bx - 104) * 2048 + tid * 8;
#pragma unroll
        for (int i = 0; i < 8; ++i) {
            int o = o0 + i; int col = o >> 5, k = o & 31;
            int m = col >> 7, hh = col & 127;
            const float* Ws = (m == 0) ? WU0 : (m == 1) ? WV0 : (m == 2) ? WB0 : WC0;
            W0t[o] = (k < FIN) ? f2b(Ws[k * H + hh]) : (unsigned short)0;
        }
    }
}

// ---------------- fully fused GNN (MFMA proj, adjacency-list message passing) ----------------
// one block per batch, 512 threads (8 waves), ~78 KB LDS  [round-7 proven]
__global__ __launch_bounds__(512) void k_gnn(const float* __restrict__ x,
        const int* __restrict__ ei, const int* __restrict__ si,
        const float* __restrict__ embed, const float* __restrict__ WA0,
        const unsigned short* __restrict__ W0t,
        const unsigned short* __restrict__ Wt640,
        unsigned short* __restrict__ Abf) {
    int b = blockIdx.x, tid = threadIdx.x;
    __shared__ unsigned short xb[48 * 40];      // x bf16, rows 40-47 & k 16-31 zero
    __shared__ unsigned short uvbc[V * 512];    // [row][m*128+h] (L0, then L1)
    __shared__ unsigned short x1l[64 * X1LD];   // rows 0-39 x1; 48-59 relu(e0); rest 0
    __shared__ float gL[NSW * H];               // gates (L0, then L1)
    __shared__ float sA1l[NSW * H];
    __shared__ int   nbr[V][MAXD];
    __shared__ int   deg[V];

    int h = tid & 127, sub = tid >> 7;
    int lane = tid & 63, wv = tid >> 6;
    int lr = lane & 15, lk = lane >> 4;
    int n0w = wv * 64;

    // ---- phase 1: load x (bf16, padded), zero deg + x1l pad rows ----
    for (int o = tid; o < 48 * 32; o += 512) {
        int r = o >> 5, k = o & 31;
        float v = (r < V && k < FIN) ? x[(size_t)b * V * FIN + r * FIN + k] : 0.f;
        xb[r * 40 + k] = f2b(v);
    }
    if (tid < V) deg[tid] = 0;
    for (int o = tid; o < 12 * 128; o += 512) {
        int rr = o >> 7;
        int row = (rr < 8) ? 40 + rr : 60 + (rr - 8);
        x1l[row * X1LD + (o & 127)] = 0;
    }
    __syncthreads();

    // ---- phase 2: adjacency build + proj0 MFMA -> uvbc(L0) ----
    if (tid < NE) {
        int i = ei[tid], j = ei[NE + tid];
        int p = atomicAdd(&deg[i], 1); if (p < MAXD) nbr[i][p] = j;
        int q = atomicAdd(&deg[j], 1); if (q < MAXD) nbr[j][q] = i;
    } else if (tid < NE + NSW) {
        int k = tid - NE;
        int i = si[k], j = si[NSW + k];
        int p = atomicAdd(&deg[i], 1); if (p < MAXD) nbr[i][p] = j | ((k + 1) << 8);
    }
    {
        f32x4 acc[3][4];
#pragma unroll
        for (int rf = 0; rf < 3; ++rf)
#pragma unroll
            for (int cf = 0; cf < 4; ++cf) acc[rf][cf] = (f32x4){0.f, 0.f, 0.f, 0.f};
        int kseg = lk * 8;
        bf16x8 a0 = *(const bf16x8*)&xb[lr * 40 + kseg];
        bf16x8 a1 = *(const bf16x8*)&xb[(16 + lr) * 40 + kseg];
        bf16x8 a2 = *(const bf16x8*)&xb[(32 + lr) * 40 + kseg];
#pragma unroll
        for (int cf = 0; cf < 4; ++cf) {
            bf16x8 bf = *(const bf16x8*)&W0t[(n0w + cf * 16 + lr) * 32 + kseg];
            acc[0][cf] = __builtin_amdgcn_mfma_f32_16x16x32_bf16(a0, bf, acc[0][cf], 0, 0, 0);
            acc[1][cf] = __builtin_amdgcn_mfma_f32_16x16x32_bf16(a1, bf, acc[1][cf], 0, 0, 0);
            acc[2][cf] = __builtin_amdgcn_mfma_f32_16x16x32_bf16(a2, bf, acc[2][cf], 0, 0, 0);
        }
#pragma unroll
        for (int rf = 0; rf < 3; ++rf)
#pragma unroll
            for (int cf = 0; cf < 4; ++cf)
#pragma unroll
                for (int r = 0; r < 4; ++r) {
                    int row = rf * 16 + lk * 4 + r;
                    if (row < V) uvbc[row * 512 + n0w + cf * 16 + lr] = f2b(acc[rf][cf][r]);
                }
    }
    __syncthreads();

    // ---- phase 3: layer-0 gates -> gL; relu(e0) -> x1l rows 48..59 ----
    {
        float sA0 = 0.f;
#pragma unroll
        for (int f = 0; f < FIN; ++f) sA0 += embed[FIN + f] * WA0[f * H + h];
        for (int k = sub; k < NSW; k += 4) {
            int i = si[k], j = si[NSW + k];
            float e0 = sA0 + b2f(uvbc[i * 512 + 256 + h]) + b2f(uvbc[j * 512 + 384 + h]);
            gL[k * H + h] = sigmoidf(e0);
            x1l[(48 + k) * X1LD + h] = f2b(fmaxf(e0, 0.f));
        }
    }
    __syncthreads();

    // ---- phase 4: x1 via adjacency -> x1l rows 0..39 ----
    for (int i = sub * 10; i < sub * 10 + 10; ++i) {
        float acc = b2f(uvbc[i * 512 + h]);          // Ux
        int d = deg[i]; if (d > MAXD) d = MAXD;
        for (int p = 0; p < d; ++p) {
            int ent = nbr[i][p];
            float vv = b2f(uvbc[(ent & 255) * 512 + 128 + h]);   // Vx[j]
            int g = ent >> 8;
            if (g) vv *= gL[(g - 1) * H + h];
            acc += vv;
        }
        x1l[i * X1LD + h] = f2b(fmaxf(acc, 0.f));    // layer 0: no residual
    }
    __syncthreads();

    // ---- phase 5: proj1 + sA1 MFMA -> uvbc(L1), sA1l ----
    {
        f32x4 acc[3][4], accs = (f32x4){0.f, 0.f, 0.f, 0.f};
#pragma unroll
        for (int rf = 0; rf < 3; ++rf)
#pragma unroll
            for (int cf = 0; cf < 4; ++cf) acc[rf][cf] = (f32x4){0.f, 0.f, 0.f, 0.f};
#pragma unroll
        for (int kk = 0; kk < 4; ++kk) {
            int kseg = kk * 32 + lk * 8;
            bf16x8 a0 = *(const bf16x8*)&x1l[lr * X1LD + kseg];
            bf16x8 a1 = *(const bf16x8*)&x1l[(16 + lr) * X1LD + kseg];
            bf16x8 a2 = *(const bf16x8*)&x1l[(32 + lr) * X1LD + kseg];
            bf16x8 as = *(const bf16x8*)&x1l[(48 + lr) * X1LD + kseg];
#pragma unroll
            for (int cf = 0; cf < 4; ++cf) {
                bf16x8 bf = *(const bf16x8*)&Wt640[(size_t)(n0w + cf * 16 + lr) * H + kseg];
                acc[0][cf] = __builtin_amdgcn_mfma_f32_16x16x32_bf16(a0, bf, acc[0][cf], 0, 0, 0);
                acc[1][cf] = __builtin_amdgcn_mfma_f32_16x16x32_bf16(a1, bf, acc[1][cf], 0, 0, 0);
                acc[2][cf] = __builtin_amdgcn_mfma_f32_16x16x32_bf16(a2, bf, acc[2][cf], 0, 0, 0);
            }
            bf16x8 bs = *(const bf16x8*)&Wt640[(size_t)(512 + wv * 16 + lr) * H + kseg];
            accs = __builtin_amdgcn_mfma_f32_16x16x32_bf16(as, bs, accs, 0, 0, 0);
        }
#pragma unroll
        for (int rf = 0; rf < 3; ++rf)
#pragma unroll
            for (int cf = 0; cf < 4; ++cf)
#pragma unroll
                for (int r = 0; r < 4; ++r) {
                    int row = rf * 16 + lk * 4 + r;
                    if (row < V) uvbc[row * 512 + n0w + cf * 16 + lr] = f2b(acc[rf][cf][r]);
                }
#pragma unroll
        for (int r = 0; r < 4; ++r) {
            int sr = lk * 4 + r;
            if (sr < NSW) sA1l[sr * H + wv * 16 + lr] = accs[r];
        }
    }
    __syncthreads();

    // ---- phase 6: layer-1 gates -> gL; s2 switch rows -> Abf ----
    for (int k = sub; k < NSW; k += 4) {
        int i = si[k], j = si[NSW + k];
        float e1 = sA1l[k * H + h] + b2f(uvbc[i * 512 + 256 + h]) + b2f(uvbc[j * 512 + 384 + h]);
        gL[k * H + h] = sigmoidf(e1);
        float s1 = b2f(x1l[(48 + k) * X1LD + h]);
        Abf[(size_t)b * MLP_IN + k * H + h] = f2b(s1 + fmaxf(e1, 0.f));
    }
    __syncthreads();

    // ---- phase 7: x2 via adjacency (residual) -> Abf ----
    for (int i = sub * 10; i < sub * 10 + 10; ++i) {
        float acc = b2f(uvbc[i * 512 + h]);
        int d = deg[i]; if (d > MAXD) d = MAXD;
        for (int p = 0; p < d; ++p) {
            int ent = nbr[i][p];
            float vv = b2f(uvbc[(ent & 255) * 512 + 128 + h]);
            int g = ent >> 8;
            if (g) vv *= gL[(g - 1) * H + h];
            acc += vv;
        }
        float x2 = b2f(x1l[i * X1LD + h]) + fmaxf(acc, 0.f);
        Abf[(size_t)b * MLP_IN + NSW * H + i * H + h] = f2b(x2);
    }
}

// ---------------- MLP GEMM: fused W1 transpose+convert, W1 staged exactly ONCE ----------------
// partial[z][m][n] = Abf[m][k-chunk] @ W1[k-chunk][n]
// grid(16, 1, NCH), block 256 = 4 waves; BLOCK tile 256 rows x 64 cols (all M rows);
// wave tile 64x64 (4x4 frags, 16 MFMA/k-step).
__global__ __launch_bounds__(256) void k_mlp(const unsigned short* __restrict__ A,
        const float* __restrict__ W1, float* __restrict__ partial) {
    const int NK = 16;
    int tid = threadIdx.x;
    int lane = tid & 63, wvv = tid >> 6;          // wave -> rows wvv*64..+63
    int n0 = blockIdx.x * 64;
    int kbase = blockIdx.z * NK * 32;

    __shared__ __align__(16) unsigned short a_lds[256 * 40];   // 20.5 KB
    __shared__ __align__(16) unsigned short b_lds[64 * 40];    //  5 KB

    f32x4 acc[4][4];
#pragma unroll
    for (int rf = 0; rf < 4; ++rf)
#pragma unroll
        for (int cf = 0; cf < 4; ++cf) acc[rf][cf] = (f32x4){0.f, 0.f, 0.f, 0.f};

    // A staging: thread -> rows {srow, srow+64, srow+128, srow+192}, 8 consecutive k
    int srow = tid >> 2, sseg = tid & 3;
    const unsigned short* gA = A + (size_t)srow * MLP_IN + kbase + sseg * 8;
    int lwsA = srow * 40 + sseg * 8;

    // B staging: thread -> (bcol, 8 consecutive k rows); W1 row-major [k][n]
    int bcol = tid & 63, bkg = tid >> 6;
    const float* gW = W1 + (size_t)(kbase + bkg * 8) * MLP_HID + n0 + bcol;
    int lwsB = bcol * 40 + bkg * 8;

    int lr = lane & 15, lk = lane >> 4;
    int a_off = (wvv * 64 + lr) * 40 + lk * 8;
    int b_off = lr * 40 + lk * 8;

    int4 ra[4];
    float rfv[8];
#pragma unroll
    for (int g = 0; g < 4; ++g)
        ra[g] = *(const int4*)(gA + (size_t)g * 64 * MLP_IN);
#pragma unroll
    for (int i = 0; i < 8; ++i) rfv[i] = gW[(size_t)i * MLP_HID];

    for (int kk = 0; kk < NK; ++kk) {
#pragma unroll
        for (int g = 0; g < 4; ++g)
            *(int4*)&a_lds[lwsA + g * 64 * 40] = ra[g];
        {
            union { unsigned short us[8]; int4 v; } pk;
#pragma unroll
            for (int i = 0; i < 8; ++i) pk.us[i] = f2b(rfv[i]);
            *(int4*)&b_lds[lwsB] = pk.v;
        }
        __syncthreads();
        if (kk + 1 < NK) {
#pragma unroll
            for (int g = 0; g < 4; ++g)
                ra[g] = *(const int4*)(gA + (size_t)g * 64 * MLP_IN + (kk + 1) * 32);
            const float* g2 = gW + (size_t)(kk + 1) * 32 * MLP_HID;
#pragma unroll
            for (int i = 0; i < 8; ++i) rfv[i] = g2[(size_t)i * MLP_HID];
        }
        bf16x8 af[4], bf[4];
#pragma unroll
        for (int rf = 0; rf < 4; ++rf) af[rf] = *(const bf16x8*)&a_lds[a_off + rf * 16 * 40];
#pragma unroll
        for (int cf = 0; cf < 4; ++cf) bf[cf] = *(const bf16x8*)&b_lds[b_off + cf * 16 * 40];
#pragma unroll
        for (int rf = 0; rf < 4; ++rf)
#pragma unroll
            for (int cf = 0; cf < 4; ++cf)
                acc[rf][cf] = __builtin_amdgcn_mfma_f32_16x16x32_bf16(af[rf], bf[cf], acc[rf][cf], 0, 0, 0);
        __syncthreads();
    }

    float* dst = partial + (size_t)blockIdx.z * 256 * MLP_HID;
#pragma unroll
    for (int rf = 0; rf < 4; ++rf)
#pragma unroll
        for (int cf = 0; cf < 4; ++cf) {
            int row = wvv * 64 + rf * 16 + lk * 4;
            int col = n0 + cf * 16 + lr;
#pragma unroll
            for (int e = 0; e < 4; ++e)
                dst[(size_t)(row + e) * MLP_HID + col] = acc[rf][cf][e];
        }
}

// ---------------- generic bf16 MFMA GEMM (head): f32 split-K partial out ----------------
template<int MODE>
__global__ __launch_bounds__(256) void k_gemm(const unsigned short* __restrict__ A,
        const unsigned short* __restrict__ Bt, void* __restrict__ Cout,
        int K, int nk, int ldc) {
    int tid = threadIdx.x;
    int lane = tid & 63, wv = tid >> 6;
    int wr = (wv >> 1) * 32, wc = (wv & 1) * 32;
    int n0 = blockIdx.x * 64, m0 = blockIdx.y * 64;
    size_t kbase = (size_t)blockIdx.z * nk * 32;

    __shared__ __align__(16) unsigned short a_lds[64 * 40];
    __shared__ __align__(16) unsigned short b_lds[64 * 40];

    f32x4 acc00 = {0,0,0,0}, acc01 = {0,0,0,0}, acc10 = {0,0,0,0}, acc11 = {0,0,0,0};

    int srow = tid >> 2, sseg = tid & 3;
    const int4* gA = (const int4*)(A + (size_t)(m0 + srow) * K + kbase + sseg * 8);
    const int4* gB = (const int4*)(Bt + (size_t)(n0 + srow) * K + kbase + sseg * 8);
    int lws = srow * 40 + sseg * 8;

    int a_off = (wr + (lane & 15)) * 40 + (lane >> 4) * 8;
    int b_off = (wc + (lane & 15)) * 40 + (lane >> 4) * 8;

    int4 ra = gA[0], rb = gB[0];
    for (int kk = 0; kk < nk; ++kk) {
        *(int4*)&a_lds[lws] = ra;
        *(int4*)&b_lds[lws] = rb;
        __syncthreads();
        if (kk + 1 < nk) { ra = gA[(kk + 1) * 4]; rb = gB[(kk + 1) * 4]; }
        bf16x8 a0 = *(const bf16x8*)&a_lds[a_off];
        bf16x8 a1 = *(const bf16x8*)&a_lds[a_off + 16 * 40];
        bf16x8 b0 = *(const bf16x8*)&b_lds[b_off];
        bf16x8 b1 = *(const bf16x8*)&b_lds[b_off + 16 * 40];
        acc00 = __builtin_amdgcn_mfma_f32_16x16x32_bf16(a0, b0, acc00, 0, 0, 0);
        acc01 = __builtin_amdgcn_mfma_f32_16x16x32_bf16(a0, b1, acc01, 0, 0, 0);
        acc10 = __builtin_amdgcn_mfma_f32_16x16x32_bf16(a1, b0, acc10, 0, 0, 0);
        acc11 = __builtin_amdgcn_mfma_f32_16x16x32_bf16(a1, b1, acc11, 0, 0, 0);
        __syncthreads();
    }

    int crow = (lane >> 4) * 4, ccol = lane & 15;
    int row0 = m0 + wr + crow, row1 = row0 + 16;
    int col0 = n0 + wc + ccol, col1 = col0 + 16;
    float* dst = (float*)Cout + (size_t)blockIdx.z * (gridDim.y * 64) * ldc;
#pragma unroll
    for (int r = 0; r < 4; ++r) {
        dst[(size_t)(row0 + r) * ldc + col0] = acc00[r];
        dst[(size_t)(row0 + r) * ldc + col1] = acc01[r];
        dst[(size_t)(row1 + r) * ldc + col0] = acc10[r];
        dst[(size_t)(row1 + r) * ldc + col1] = acc11[r];
    }
}

// reduce MLP split-K partials + bias + relu -> bf16 hidden
__global__ void k_mred(const float* __restrict__ partial, const float* __restrict__ b1,
                       unsigned short* __restrict__ hiddenb) {
    int i = blockIdx.x * 256 + threadIdx.x;   // < 256*1024
    float s = b1[i & (MLP_HID - 1)];
#pragma unroll
    for (int z = 0; z < NCH; ++z) s += partial[(size_t)z * 256 * MLP_HID + i];
    hiddenb[i] = f2b(fmaxf(s, 0.f));
}

// ---------------- finalize: reduce head partials + postprocess ----------------
__global__ __launch_bounds__(128) void k_fin(const float* __restrict__ partial2,
        const float* __restrict__ b2, const float* __restrict__ A,
        const float* __restrict__ x_mod, float* __restrict__ outp) {
    int b = blockIdx.x;
    int tid = threadIdx.x;
    __shared__ float o[OUTD];
    __shared__ float gt[M], vv[V], pfc[M], qfc[M];

    if (tid < OUTD) {
        float s = b2[tid];
#pragma unroll
        for (int z = 0; z < 4; ++z) s += partial2[(size_t)z * 256 * 128 + b * 128 + tid];
        o[tid] = s;
    }
    __syncthreads();

    if (tid < M) {
        float g = (tid < M - NSW) ? 1.0f : sigmoidf(o[M + V + (tid - (M - NSW))]);
        gt[tid] = g;
        pfc[tid] = g * o[tid];
    }
    if (tid < V) vv[tid] = (tid == 0) ? 1.0f : o[M + tid];
    __syncthreads();

    if (tid < M) {
        float acc = 0.f;
        for (int x = 0; x < V; ++x) acc += vv[x] * A[x * M + tid];
        qfc[tid] = gt[tid] * acc;
    }
    __syncthreads();

    float* zb = outp + (size_t)b * ZDIM;
    if (tid < M) zb[tid] = pfc[tid];
    if (tid < V) zb[M + tid] = vv[tid];
    if (tid < M) zb[M + V + tid] = gt[tid];

    float* zcb = outp + (size_t)B * ZDIM + (size_t)b * ZCDIM;
    if (tid < M) zcb[tid] = qfc[tid];
    if (tid < V) {
        float accp = 0.f, accq = 0.f;
        for (int m = 0; m < M; ++m) {
            float a = A[tid * M + m];
            accp += a * pfc[m];
            accq += a * qfc[m];
        }
        zcb[M + tid]     = x_mod[(size_t)(b * V + tid) * FIN + 0] + accp;
        zcb[M + V + tid] = x_mod[(size_t)(b * V + tid) * FIN + 1] + accq;
    }
}

extern "C" void kernel_launch(void* const* d_in, const int* in_sizes, int n_in,
                              void* d_out, int out_size, void* d_ws, size_t ws_size,
                              hipStream_t stream) {
    const float* x_mod = (const float*)d_in[0];
    const int*   ei    = (const int*)d_in[1];
    const int*   si    = (const int*)d_in[2];
    const float* A     = (const float*)d_in[3];
    const float* embed = (const float*)d_in[4];
    const float* WU0   = (const float*)d_in[5];
    const float* WV0   = (const float*)d_in[6];
    const float* WA0   = (const float*)d_in[7];
    const float* WB0   = (const float*)d_in[8];
    const float* WC0   = (const float*)d_in[9];
    const float* WU1   = (const float*)d_in[10];
    const float* WV1   = (const float*)d_in[11];
    const float* WA1   = (const float*)d_in[12];
    const float* WB1   = (const float*)d_in[13];
    const float* WC1   = (const float*)d_in[14];
    const float* W1    = (const float*)d_in[15];
    const float* b1    = (const float*)d_in[16];
    const float* W2    = (const float*)d_in[17];
    const float* b2    = (const float*)d_in[18];
    float* out = (float*)d_out;

    // Workspace layout (byte offsets), ~18.5 MB
    char* ws = (char*)d_ws;
    unsigned short* W0t      = (unsigned short*)(ws + 0);          //    32,768
    unsigned short* Wt640    = (unsigned short*)(ws + 32768);      //   163,840
    unsigned short* W2t      = (unsigned short*)(ws + 196608);     //   262,144
    unsigned short* Abf      = (unsigned short*)(ws + 458752);     // 3,407,872 (rows >=200 stale, benign)
    float*          partialM = (float*)(ws + 3866624);             // 13,631,488
    unsigned short* hiddenb  = (unsigned short*)(ws + 17498112);   //   524,288
    float*          partial2 = (float*)(ws + 18022400);            //   524,288

    // 1. small weight prep (W0t, Wt640, W2t)
    k_prep<<<112, 256, 0, stream>>>(WU0, WV0, WB0, WC0, WU1, WV1, WB1, WC1, WA1, W2,
                                    W0t, Wt640, W2t);
    // 2. fully fused GNN (both layers, MFMA projections) -> Abf
    k_gnn<<<B, 512, 0, stream>>>(x_mod, ei, si, embed, WA0, W0t, Wt640, Abf);
    // 3. MLP hidden: (256x6656) @ W1 (f32, transposed on the fly), split-K=13
    //    W1 staged exactly once (y=1: block tile covers all 256 rows)
    k_mlp<<<dim3(16, 1, NCH), 256, 0, stream>>>(Abf, W1, partialM);
    // 4. reduce + bias + relu -> hiddenb bf16
    k_mred<<<256 * MLP_HID / 256, 256, 0, stream>>>(partialM, b1, hiddenb);
    // 5. head GEMM: (256x1024) @ (1024x128), split-K=4 -> partial2
    k_gemm<2><<<dim3(2, 4, 4), 256, 0, stream>>>(hiddenb, W2t, partial2, MLP_HID, 8, 128);
    // 6. finalize: reduce + graph postprocess
    k_fin<<<B, 128, 0, stream>>>(partial2, b2, A, x_mod, out);
}

// Round 10
// 65.561 us; speedup vs baseline: 1.0812x; 1.0362x over previous
//
#include <hip/hip_runtime.h>
#include <math.h>

// Problem constants
#define B       200
#define V       40
#define FIN     16
#define H       128
#define NSW     12
#define NE      40
#define M       52      // NE + NSW
#define MLP_HID 1024
#define OUTD    104     // M + V + NSW
#define MLP_IN  6656    // (NSW + V) * H
#define ZDIM    144
#define ZCDIM   132
#define NCH     13      // MLP split-K chunks
#define X1LD    136     // x1 LDS row stride (shorts)
#define MAXD    16      // max adjacency degree

typedef __attribute__((ext_vector_type(8))) short bf16x8;
typedef __attribute__((ext_vector_type(4))) float f32x4;

__device__ __forceinline__ float sigmoidf(float x) {
    return 1.0f / (1.0f + expf(-x));
}
__device__ __forceinline__ unsigned short f2b(float x) {  // fp32 -> bf16 RNE
    unsigned int u = __float_as_uint(x);
    u += 0x7fffu + ((u >> 16) & 1u);
    return (unsigned short)(u >> 16);
}
__device__ __forceinline__ float b2f(unsigned short s) {
    return __uint_as_float(((unsigned int)s) << 16);
}

// ---------------- weight prep (small mats; W1 handled inside k_mlp) ----------------
// bx<64: W2 (1024x104) -> W2t[col][k] (cols>=104 zero), 128x1024
// 64<=bx<104: {WU1,WV1,WB1,WC1,WA1} -> Wt640[col][f], 640x128
// 104<=bx<112: {WU0,WV0,WB0,WC0} -> W0t[col][k] 512x32, k>=16 zero
__global__ __launch_bounds__(256) void k_prep(
        const float* __restrict__ WU0, const float* __restrict__ WV0,
        const float* __restrict__ WB0, const float* __restrict__ WC0,
        const float* __restrict__ WU1, const float* __restrict__ WV1,
        const float* __restrict__ WB1, const float* __restrict__ WC1,
        const float* __restrict__ WA1, const float* __restrict__ W2,
        unsigned short* __restrict__ W0t, unsigned short* __restrict__ Wt640,
        unsigned short* __restrict__ W2t) {
    int bx = blockIdx.x, tid = threadIdx.x;
    if (bx < 64) {
        int o0 = bx * 2048 + tid * 8;
#pragma unroll
        for (int i = 0; i < 8; ++i) {
            int o = o0 + i; int col = o >> 10, k = o & 1023;
            W2t[o] = (col < OUTD) ? f2b(W2[(size_t)k * OUTD + col]) : (unsigned short)0;
        }
    } else if (bx < 104) {
        int o0 = (bx - 64) * 2048 + tid * 8;
#pragma unroll
        for (int i = 0; i < 8; ++i) {
            int o = o0 + i; int col = o >> 7, f = o & 127;
            int m = col >> 7, hh = col & 127;
            const float* Ws = (m == 0) ? WU1 : (m == 1) ? WV1 : (m == 2) ? WB1
                            : (m == 3) ? WC1 : WA1;
            Wt640[o] = f2b(Ws[f * H + hh]);
        }
    } else {
        int o0 = (bx - 104) * 2048 + tid * 8;
#pragma unroll
        for (int i = 0; i < 8; ++i) {
            int o = o0 + i; int col = o >> 5, k = o & 31;
            int m = col >> 7, hh = col & 127;
            const float* Ws = (m == 0) ? WU0 : (m == 1) ? WV0 : (m == 2) ? WB0 : WC0;
            W0t[o] = (k < FIN) ? f2b(Ws[k * H + hh]) : (unsigned short)0;
        }
    }
}

// ---------------- fully fused GNN (MFMA proj, adjacency-list message passing) ----------------
// one block per batch, 512 threads (8 waves), ~78 KB LDS  [round-7 proven, unchanged]
__global__ __launch_bounds__(512) void k_gnn(const float* __restrict__ x,
        const int* __restrict__ ei, const int* __restrict__ si,
        const float* __restrict__ embed, const float* __restrict__ WA0,
        const unsigned short* __restrict__ W0t,
        const unsigned short* __restrict__ Wt640,
        unsigned short* __restrict__ Abf) {
    int b = blockIdx.x, tid = threadIdx.x;
    __shared__ unsigned short xb[48 * 40];      // x bf16, rows 40-47 & k 16-31 zero
    __shared__ unsigned short uvbc[V * 512];    // [row][m*128+h] (L0, then L1)
    __shared__ unsigned short x1l[64 * X1LD];   // rows 0-39 x1; 48-59 relu(e0); rest 0
    __shared__ float gL[NSW * H];               // gates (L0, then L1)
    __shared__ float sA1l[NSW * H];
    __shared__ int   nbr[V][MAXD];
    __shared__ int   deg[V];

    int h = tid & 127, sub = tid >> 7;
    int lane = tid & 63, wv = tid >> 6;
    int lr = lane & 15, lk = lane >> 4;
    int n0w = wv * 64;

    // ---- phase 1: load x (bf16, padded), zero deg + x1l pad rows ----
    for (int o = tid; o < 48 * 32; o += 512) {
        int r = o >> 5, k = o & 31;
        float v = (r < V && k < FIN) ? x[(size_t)b * V * FIN + r * FIN + k] : 0.f;
        xb[r * 40 + k] = f2b(v);
    }
    if (tid < V) deg[tid] = 0;
    for (int o = tid; o < 12 * 128; o += 512) {
        int rr = o >> 7;
        int row = (rr < 8) ? 40 + rr : 60 + (rr - 8);
        x1l[row * X1LD + (o & 127)] = 0;
    }
    __syncthreads();

    // ---- phase 2: adjacency build + proj0 MFMA -> uvbc(L0) ----
    if (tid < NE) {
        int i = ei[tid], j = ei[NE + tid];
        int p = atomicAdd(&deg[i], 1); if (p < MAXD) nbr[i][p] = j;
        int q = atomicAdd(&deg[j], 1); if (q < MAXD) nbr[j][q] = i;
    } else if (tid < NE + NSW) {
        int k = tid - NE;
        int i = si[k], j = si[NSW + k];
        int p = atomicAdd(&deg[i], 1); if (p < MAXD) nbr[i][p] = j | ((k + 1) << 8);
    }
    {
        f32x4 acc[3][4];
#pragma unroll
        for (int rf = 0; rf < 3; ++rf)
#pragma unroll
            for (int cf = 0; cf < 4; ++cf) acc[rf][cf] = (f32x4){0.f, 0.f, 0.f, 0.f};
        int kseg = lk * 8;
        bf16x8 a0 = *(const bf16x8*)&xb[lr * 40 + kseg];
        bf16x8 a1 = *(const bf16x8*)&xb[(16 + lr) * 40 + kseg];
        bf16x8 a2 = *(const bf16x8*)&xb[(32 + lr) * 40 + kseg];
#pragma unroll
        for (int cf = 0; cf < 4; ++cf) {
            bf16x8 bf = *(const bf16x8*)&W0t[(n0w + cf * 16 + lr) * 32 + kseg];
            acc[0][cf] = __builtin_amdgcn_mfma_f32_16x16x32_bf16(a0, bf, acc[0][cf], 0, 0, 0);
            acc[1][cf] = __builtin_amdgcn_mfma_f32_16x16x32_bf16(a1, bf, acc[1][cf], 0, 0, 0);
            acc[2][cf] = __builtin_amdgcn_mfma_f32_16x16x32_bf16(a2, bf, acc[2][cf], 0, 0, 0);
        }
#pragma unroll
        for (int rf = 0; rf < 3; ++rf)
#pragma unroll
            for (int cf = 0; cf < 4; ++cf)
#pragma unroll
                for (int r = 0; r < 4; ++r) {
                    int row = rf * 16 + lk * 4 + r;
                    if (row < V) uvbc[row * 512 + n0w + cf * 16 + lr] = f2b(acc[rf][cf][r]);
                }
    }
    __syncthreads();

    // ---- phase 3: layer-0 gates -> gL; relu(e0) -> x1l rows 48..59 ----
    {
        float sA0 = 0.f;
#pragma unroll
        for (int f = 0; f < FIN; ++f) sA0 += embed[FIN + f] * WA0[f * H + h];
        for (int k = sub; k < NSW; k += 4) {
            int i = si[k], j = si[NSW + k];
            float e0 = sA0 + b2f(uvbc[i * 512 + 256 + h]) + b2f(uvbc[j * 512 + 384 + h]);
            gL[k * H + h] = sigmoidf(e0);
            x1l[(48 + k) * X1LD + h] = f2b(fmaxf(e0, 0.f));
        }
    }
    __syncthreads();

    // ---- phase 4: x1 via adjacency -> x1l rows 0..39 ----
    for (int i = sub * 10; i < sub * 10 + 10; ++i) {
        float acc = b2f(uvbc[i * 512 + h]);          // Ux
        int d = deg[i]; if (d > MAXD) d = MAXD;
        for (int p = 0; p < d; ++p) {
            int ent = nbr[i][p];
            float vv = b2f(uvbc[(ent & 255) * 512 + 128 + h]);   // Vx[j]
            int g = ent >> 8;
            if (g) vv *= gL[(g - 1) * H + h];
            acc += vv;
        }
        x1l[i * X1LD + h] = f2b(fmaxf(acc, 0.f));    // layer 0: no residual
    }
    __syncthreads();

    // ---- phase 5: proj1 + sA1 MFMA -> uvbc(L1), sA1l ----
    {
        f32x4 acc[3][4], accs = (f32x4){0.f, 0.f, 0.f, 0.f};
#pragma unroll
        for (int rf = 0; rf < 3; ++rf)
#pragma unroll
            for (int cf = 0; cf < 4; ++cf) acc[rf][cf] = (f32x4){0.f, 0.f, 0.f, 0.f};
#pragma unroll
        for (int kk = 0; kk < 4; ++kk) {
            int kseg = kk * 32 + lk * 8;
            bf16x8 a0 = *(const bf16x8*)&x1l[lr * X1LD + kseg];
            bf16x8 a1 = *(const bf16x8*)&x1l[(16 + lr) * X1LD + kseg];
            bf16x8 a2 = *(const bf16x8*)&x1l[(32 + lr) * X1LD + kseg];
            bf16x8 as = *(const bf16x8*)&x1l[(48 + lr) * X1LD + kseg];
#pragma unroll
            for (int cf = 0; cf < 4; ++cf) {
                bf16x8 bf = *(const bf16x8*)&Wt640[(size_t)(n0w + cf * 16 + lr) * H + kseg];
                acc[0][cf] = __builtin_amdgcn_mfma_f32_16x16x32_bf16(a0, bf, acc[0][cf], 0, 0, 0);
                acc[1][cf] = __builtin_amdgcn_mfma_f32_16x16x32_bf16(a1, bf, acc[1][cf], 0, 0, 0);
                acc[2][cf] = __builtin_amdgcn_mfma_f32_16x16x32_bf16(a2, bf, acc[2][cf], 0, 0, 0);
            }
            bf16x8 bs = *(const bf16x8*)&Wt640[(size_t)(512 + wv * 16 + lr) * H + kseg];
            accs = __builtin_amdgcn_mfma_f32_16x16x32_bf16(as, bs, accs, 0, 0, 0);
        }
#pragma unroll
        for (int rf = 0; rf < 3; ++rf)
#pragma unroll
            for (int cf = 0; cf < 4; ++cf)
#pragma unroll
                for (int r = 0; r < 4; ++r) {
                    int row = rf * 16 + lk * 4 + r;
                    if (row < V) uvbc[row * 512 + n0w + cf * 16 + lr] = f2b(acc[rf][cf][r]);
                }
#pragma unroll
        for (int r = 0; r < 4; ++r) {
            int sr = lk * 4 + r;
            if (sr < NSW) sA1l[sr * H + wv * 16 + lr] = accs[r];
        }
    }
    __syncthreads();

    // ---- phase 6: layer-1 gates -> gL; s2 switch rows -> Abf ----
    for (int k = sub; k < NSW; k += 4) {
        int i = si[k], j = si[NSW + k];
        float e1 = sA1l[k * H + h] + b2f(uvbc[i * 512 + 256 + h]) + b2f(uvbc[j * 512 + 384 + h]);
        gL[k * H + h] = sigmoidf(e1);
        float s1 = b2f(x1l[(48 + k) * X1LD + h]);
        Abf[(size_t)b * MLP_IN + k * H + h] = f2b(s1 + fmaxf(e1, 0.f));
    }
    __syncthreads();

    // ---- phase 7: x2 via adjacency (residual) -> Abf ----
    for (int i = sub * 10; i < sub * 10 + 10; ++i) {
        float acc = b2f(uvbc[i * 512 + h]);
        int d = deg[i]; if (d > MAXD) d = MAXD;
        for (int p = 0; p < d; ++p) {
            int ent = nbr[i][p];
            float vv = b2f(uvbc[(ent & 255) * 512 + 128 + h]);
            int g = ent >> 8;
            if (g) vv *= gL[(g - 1) * H + h];
            acc += vv;
        }
        float x2 = b2f(x1l[i * X1LD + h]) + fmaxf(acc, 0.f);
        Abf[(size_t)b * MLP_IN + NSW * H + i * H + h] = f2b(x2);
    }
}

// ---------------- MLP GEMM: fused W1 transpose+convert ----------------
// partial[z][m][n] = Abf[m][k-chunk] @ W1[k-chunk][n]
// grid(16, 2, NCH) = 416 blocks, 256 thr = 4 waves.
// block tile 128 rows x 64 cols; wave tile 32x64 (2x4 frags, 8 MFMA/k-step).
// W1 duplication 2x (vs r7's 4x) at IDENTICAL wave count (r9 lesson: occupancy first).
__global__ __launch_bounds__(256) void k_mlp(const unsigned short* __restrict__ A,
        const float* __restrict__ W1, float* __restrict__ partial) {
    const int NK = 16;
    int tid = threadIdx.x;
    int lane = tid & 63, wvv = tid >> 6;          // wave -> rows wvv*32..+31
    int n0 = blockIdx.x * 64;                     // 16 col tiles
    int m0 = blockIdx.y * 128;                    // 2 row tiles
    int kbase = blockIdx.z * NK * 32;             // 13 chunks of 512

    __shared__ __align__(16) unsigned short a_lds[128 * 40];   // 10 KB
    __shared__ __align__(16) unsigned short b_lds[64 * 40];    //  5 KB

    f32x4 acc[2][4];
#pragma unroll
    for (int rf = 0; rf < 2; ++rf)
#pragma unroll
        for (int cf = 0; cf < 4; ++cf) acc[rf][cf] = (f32x4){0.f, 0.f, 0.f, 0.f};

    // A staging: thread stages rows sr0 and sr0+64 (8 shorts each)
    int sr0 = tid >> 2, ss = tid & 3;
    const unsigned short* gA0 = A + (size_t)(m0 + sr0) * MLP_IN + kbase + ss * 8;
    const unsigned short* gA1 = gA0 + (size_t)64 * MLP_IN;
    int lwsA0 = sr0 * 40 + ss * 8;
    int lwsA1 = (sr0 + 64) * 40 + ss * 8;

    // B staging: thread -> (bcol, 8 consecutive k rows); W1 row-major [k][n]
    int bcol = tid & 63, bkg = tid >> 6;
    const float* gW = W1 + (size_t)(kbase + bkg * 8) * MLP_HID + n0 + bcol;
    int lwsB = bcol * 40 + bkg * 8;

    int lr = lane & 15, lk = lane >> 4;
    int a_off = (wvv * 32 + lr) * 40 + lk * 8;
    int b_off = lr * 40 + lk * 8;

    int4 ra0 = *(const int4*)gA0;
    int4 ra1 = *(const int4*)gA1;
    float rfv[8];
#pragma unroll
    for (int i = 0; i < 8; ++i) rfv[i] = gW[(size_t)i * MLP_HID];

    for (int kk = 0; kk < NK; ++kk) {
        *(int4*)&a_lds[lwsA0] = ra0;
        *(int4*)&a_lds[lwsA1] = ra1;
        {
            union { unsigned short us[8]; int4 v; } pk;
#pragma unroll
            for (int i = 0; i < 8; ++i) pk.us[i] = f2b(rfv[i]);
            *(int4*)&b_lds[lwsB] = pk.v;
        }
        __syncthreads();
        if (kk + 1 < NK) {
            ra0 = *(const int4*)(gA0 + (kk + 1) * 32);
            ra1 = *(const int4*)(gA1 + (kk + 1) * 32);
            const float* g2 = gW + (size_t)(kk + 1) * 32 * MLP_HID;
#pragma unroll
            for (int i = 0; i < 8; ++i) rfv[i] = g2[(size_t)i * MLP_HID];
        }
        bf16x8 af[2], bfv[4];
#pragma unroll
        for (int rf = 0; rf < 2; ++rf) af[rf] = *(const bf16x8*)&a_lds[a_off + rf * 16 * 40];
#pragma unroll
        for (int cf = 0; cf < 4; ++cf) bfv[cf] = *(const bf16x8*)&b_lds[b_off + cf * 16 * 40];
#pragma unroll
        for (int rf = 0; rf < 2; ++rf)
#pragma unroll
            for (int cf = 0; cf < 4; ++cf)
                acc[rf][cf] = __builtin_amdgcn_mfma_f32_16x16x32_bf16(af[rf], bfv[cf], acc[rf][cf], 0, 0, 0);
        __syncthreads();
    }

    float* dst = partial + (size_t)blockIdx.z * 256 * MLP_HID;
#pragma unroll
    for (int rf = 0; rf < 2; ++rf)
#pragma unroll
        for (int cf = 0; cf < 4; ++cf) {
            int row = m0 + wvv * 32 + rf * 16 + lk * 4;
            int col = n0 + cf * 16 + lr;
#pragma unroll
            for (int e = 0; e < 4; ++e)
                dst[(size_t)(row + e) * MLP_HID + col] = acc[rf][cf][e];
        }
}

// ---------------- head GEMM with fused split-K reduce + bias + relu on A ----------------
// A[m][k] = relu(b1[k] + sum_z partialM[z][m][k]) packed to bf16 in-staging.
// grid(2,4,4), 256 thr; block 64x64, wave 32x32 (2x2 frags). Writes partial2[z].
__global__ __launch_bounds__(256) void k_head(const float* __restrict__ partialM,
        const float* __restrict__ b1, const unsigned short* __restrict__ W2t,
        float* __restrict__ partial2) {
    const int NK = 8;
    int tid = threadIdx.x;
    int lane = tid & 63, wv = tid >> 6;
    int wr = (wv >> 1) * 32, wc = (wv & 1) * 32;
    int n0 = blockIdx.x * 64, m0 = blockIdx.y * 64;
    int kbase = blockIdx.z * NK * 32;

    __shared__ __align__(16) unsigned short a_lds[64 * 40];
    __shared__ __align__(16) unsigned short b_lds[64 * 40];

    f32x4 acc00 = {0,0,0,0}, acc01 = {0,0,0,0}, acc10 = {0,0,0,0}, acc11 = {0,0,0,0};

    int srow = tid >> 2, sseg = tid & 3;
    const float* gH = partialM + (size_t)(m0 + srow) * MLP_HID + kbase + sseg * 8;
    const float* gb = b1 + kbase + sseg * 8;
    int lwsA = srow * 40 + sseg * 8;

    const int4* gB = (const int4*)(W2t + (size_t)(n0 + srow) * MLP_HID + kbase + sseg * 8);

    int a_off = (wr + (lane & 15)) * 40 + (lane >> 4) * 8;
    int b_off = (wc + (lane & 15)) * 40 + (lane >> 4) * 8;

    int4 rb = gB[0];
    for (int kk = 0; kk < NK; ++kk) {
        {   // A: reduce 13 partials + bias, relu, pack bf16
            float s[8];
#pragma unroll
            for (int i = 0; i < 8; ++i) s[i] = gb[kk * 32 + i];
#pragma unroll
            for (int z = 0; z < NCH; ++z) {
                const float4* p = (const float4*)(gH + (size_t)z * 256 * MLP_HID + kk * 32);
                float4 v0 = p[0], v1 = p[1];
                s[0] += v0.x; s[1] += v0.y; s[2] += v0.z; s[3] += v0.w;
                s[4] += v1.x; s[5] += v1.y; s[6] += v1.z; s[7] += v1.w;
            }
            union { unsigned short us[8]; int4 v; } pa;
#pragma unroll
            for (int i = 0; i < 8; ++i) pa.us[i] = f2b(fmaxf(s[i], 0.f));
            *(int4*)&a_lds[lwsA] = pa.v;
        }
        *(int4*)&b_lds[lwsA] = rb;
        __syncthreads();
        if (kk + 1 < NK) rb = gB[(kk + 1) * 4];
        bf16x8 a0 = *(const bf16x8*)&a_lds[a_off];
        bf16x8 a1 = *(const bf16x8*)&a_lds[a_off + 16 * 40];
        bf16x8 b0 = *(const bf16x8*)&b_lds[b_off];
        bf16x8 b1v = *(const bf16x8*)&b_lds[b_off + 16 * 40];
        acc00 = __builtin_amdgcn_mfma_f32_16x16x32_bf16(a0, b0, acc00, 0, 0, 0);
        acc01 = __builtin_amdgcn_mfma_f32_16x16x32_bf16(a0, b1v, acc01, 0, 0, 0);
        acc10 = __builtin_amdgcn_mfma_f32_16x16x32_bf16(a1, b0, acc10, 0, 0, 0);
        acc11 = __builtin_amdgcn_mfma_f32_16x16x32_bf16(a1, b1v, acc11, 0, 0, 0);
        __syncthreads();
    }

    int crow = (lane >> 4) * 4, ccol = lane & 15;
    int row0 = m0 + wr + crow, row1 = row0 + 16;
    int col0 = n0 + wc + ccol, col1 = col0 + 16;
    float* dst = partial2 + (size_t)blockIdx.z * 256 * 128;
#pragma unroll
    for (int r = 0; r < 4; ++r) {
        dst[(size_t)(row0 + r) * 128 + col0] = acc00[r];
        dst[(size_t)(row0 + r) * 128 + col1] = acc01[r];
        dst[(size_t)(row1 + r) * 128 + col0] = acc10[r];
        dst[(size_t)(row1 + r) * 128 + col1] = acc11[r];
    }
}

// ---------------- finalize: reduce head partials + postprocess ----------------
__global__ __launch_bounds__(128) void k_fin(const float* __restrict__ partial2,
        const float* __restrict__ b2, const float* __restrict__ A,
        const float* __restrict__ x_mod, float* __restrict__ outp) {
    int b = blockIdx.x;
    int tid = threadIdx.x;
    __shared__ float o[OUTD];
    __shared__ float gt[M], vv[V], pfc[M], qfc[M];

    if (tid < OUTD) {
        float s = b2[tid];
#pragma unroll
        for (int z = 0; z < 4; ++z) s += partial2[(size_t)z * 256 * 128 + b * 128 + tid];
        o[tid] = s;
    }
    __syncthreads();

    if (tid < M) {
        float g = (tid < M - NSW) ? 1.0f : sigmoidf(o[M + V + (tid - (M - NSW))]);
        gt[tid] = g;
        pfc[tid] = g * o[tid];
    }
    if (tid < V) vv[tid] = (tid == 0) ? 1.0f : o[M + tid];
    __syncthreads();

    if (tid < M) {
        float acc = 0.f;
        for (int x = 0; x < V; ++x) acc += vv[x] * A[x * M + tid];
        qfc[tid] = gt[tid] * acc;
    }
    __syncthreads();

    float* zb = outp + (size_t)b * ZDIM;
    if (tid < M) zb[tid] = pfc[tid];
    if (tid < V) zb[M + tid] = vv[tid];
    if (tid < M) zb[M + V + tid] = gt[tid];

    float* zcb = outp + (size_t)B * ZDIM + (size_t)b * ZCDIM;
    if (tid < M) zcb[tid] = qfc[tid];
    if (tid < V) {
        float accp = 0.f, accq = 0.f;
        for (int m = 0; m < M; ++m) {
            float a = A[tid * M + m];
            accp += a * pfc[m];
            accq += a * qfc[m];
        }
        zcb[M + tid]     = x_mod[(size_t)(b * V + tid) * FIN + 0] + accp;
        zcb[M + V + tid] = x_mod[(size_t)(b * V + tid) * FIN + 1] + accq;
    }
}

extern "C" void kernel_launch(void* const* d_in, const int* in_sizes, int n_in,
                              void* d_out, int out_size, void* d_ws, size_t ws_size,
                              hipStream_t stream) {
    const float* x_mod = (const float*)d_in[0];
    const int*   ei    = (const int*)d_in[1];
    const int*   si    = (const int*)d_in[2];
    const float* A     = (const float*)d_in[3];
    const float* embed = (const float*)d_in[4];
    const float* WU0   = (const float*)d_in[5];
    const float* WV0   = (const float*)d_in[6];
    const float* WA0   = (const float*)d_in[7];
    const float* WB0   = (const float*)d_in[8];
    const float* WC0   = (const float*)d_in[9];
    const float* WU1   = (const float*)d_in[10];
    const float* WV1   = (const float*)d_in[11];
    const float* WA1   = (const float*)d_in[12];
    const float* WB1   = (const float*)d_in[13];
    const float* WC1   = (const float*)d_in[14];
    const float* W1    = (const float*)d_in[15];
    const float* b1    = (const float*)d_in[16];
    const float* W2    = (const float*)d_in[17];
    const float* b2    = (const float*)d_in[18];
    float* out = (float*)d_out;

    // Workspace layout (byte offsets), ~18 MB
    char* ws = (char*)d_ws;
    unsigned short* W0t      = (unsigned short*)(ws + 0);          //    32,768
    unsigned short* Wt640    = (unsigned short*)(ws + 32768);      //   163,840
    unsigned short* W2t      = (unsigned short*)(ws + 196608);     //   262,144
    unsigned short* Abf      = (unsigned short*)(ws + 458752);     // 3,407,872 (rows >=200 stale, benign)
    float*          partialM = (float*)(ws + 3866624);             // 13,631,488
    float*          partial2 = (float*)(ws + 17498112);            //   524,288

    // 1. small weight prep (W0t, Wt640, W2t)
    k_prep<<<112, 256, 0, stream>>>(WU0, WV0, WB0, WC0, WU1, WV1, WB1, WC1, WA1, W2,
                                    W0t, Wt640, W2t);
    // 2. fully fused GNN (both layers, MFMA projections) -> Abf
    k_gnn<<<B, 512, 0, stream>>>(x_mod, ei, si, embed, WA0, W0t, Wt640, Abf);
    // 3. MLP hidden: (256x6656) @ W1 (f32, on-the-fly transpose), split-K=13
    //    416 blocks (occupancy first — r9 lesson), W1 dup 2x (vs r7 4x)
    k_mlp<<<dim3(16, 2, NCH), 256, 0, stream>>>(Abf, W1, partialM);
    // 4. head GEMM with fused partial-reduce + bias + relu (k_mred eliminated)
    k_head<<<dim3(2, 4, 4), 256, 0, stream>>>(partialM, b1, W2t, partial2);
    // 5. finalize: reduce + graph postprocess
    k_fin<<<B, 128, 0, stream>>>(partial2, b2, A, x_mod, out);
}

// Round 11
// 58.463 us; speedup vs baseline: 1.2125x; 1.1214x over previous
//
#include <hip/hip_runtime.h>
#include <math.h>

// Problem constants
#define B       200
#define V       40
#define FIN     16
#define H       128
#define NSW     12
#define NE      40
#define M       52      // NE + NSW
#define MLP_HID 1024
#define OUTD    104     // M + V + NSW
#define MLP_IN  6656    // (NSW + V) * H
#define ZDIM    144
#define ZCDIM   132
#define NCH     26      // MLP split-K chunks (r10 lesson: k_mlp is occupancy-bound; 26 waves/CU)
#define X1LD    136     // x1 LDS row stride (shorts)
#define MAXD    16      // max adjacency degree

typedef __attribute__((ext_vector_type(8))) short bf16x8;
typedef __attribute__((ext_vector_type(4))) float f32x4;

__device__ __forceinline__ float sigmoidf(float x) {
    return 1.0f / (1.0f + expf(-x));
}
__device__ __forceinline__ unsigned short f2b(float x) {  // fp32 -> bf16 RNE
    unsigned int u = __float_as_uint(x);
    u += 0x7fffu + ((u >> 16) & 1u);
    return (unsigned short)(u >> 16);
}
__device__ __forceinline__ float b2f(unsigned short s) {
    return __uint_as_float(((unsigned int)s) << 16);
}

// ---------------- weight prep (small mats; W1 handled inside k_mlp) ----------------
// bx<64: W2 (1024x104) -> W2t[col][k] (cols>=104 zero), 128x1024
// 64<=bx<104: {WU1,WV1,WB1,WC1,WA1} -> Wt640[col][f], 640x128
// 104<=bx<112: {WU0,WV0,WB0,WC0} -> W0t[col][k] 512x32, k>=16 zero
__global__ __launch_bounds__(256) void k_prep(
        const float* __restrict__ WU0, const float* __restrict__ WV0,
        const float* __restrict__ WB0, const float* __restrict__ WC0,
        const float* __restrict__ WU1, const float* __restrict__ WV1,
        const float* __restrict__ WB1, const float* __restrict__ WC1,
        const float* __restrict__ WA1, const float* __restrict__ W2,
        unsigned short* __restrict__ W0t, unsigned short* __restrict__ Wt640,
        unsigned short* __restrict__ W2t) {
    int bx = blockIdx.x, tid = threadIdx.x;
    if (bx < 64) {
        int o0 = bx * 2048 + tid * 8;
#pragma unroll
        for (int i = 0; i < 8; ++i) {
            int o = o0 + i; int col = o >> 10, k = o & 1023;
            W2t[o] = (col < OUTD) ? f2b(W2[(size_t)k * OUTD + col]) : (unsigned short)0;
        }
    } else if (bx < 104) {
        int o0 = (bx - 64) * 2048 + tid * 8;
#pragma unroll
        for (int i = 0; i < 8; ++i) {
            int o = o0 + i; int col = o >> 7, f = o & 127;
            int m = col >> 7, hh = col & 127;
            const float* Ws = (m == 0) ? WU1 : (m == 1) ? WV1 : (m == 2) ? WB1
                            : (m == 3) ? WC1 : WA1;
            Wt640[o] = f2b(Ws[f * H + hh]);
        }
    } else {
        int o0 = (bx - 104) * 2048 + tid * 8;
#pragma unroll
        for (int i = 0; i < 8; ++i) {
            int o = o0 + i; int col = o >> 5, k = o & 31;
            int m = col >> 7, hh = col & 127;
            const float* Ws = (m == 0) ? WU0 : (m == 1) ? WV0 : (m == 2) ? WB0 : WC0;
            W0t[o] = (k < FIN) ? f2b(Ws[k * H + hh]) : (unsigned short)0;
        }
    }
}

// ---------------- fully fused GNN (MFMA proj, adjacency-list message passing) ----------------
// one block per batch, 512 threads (8 waves), ~78 KB LDS  [round-7 proven, unchanged]
__global__ __launch_bounds__(512) void k_gnn(const float* __restrict__ x,
        const int* __restrict__ ei, const int* __restrict__ si,
        const float* __restrict__ embed, const float* __restrict__ WA0,
        const unsigned short* __restrict__ W0t,
        const unsigned short* __restrict__ Wt640,
        unsigned short* __restrict__ Abf) {
    int b = blockIdx.x, tid = threadIdx.x;
    __shared__ unsigned short xb[48 * 40];      // x bf16, rows 40-47 & k 16-31 zero
    __shared__ unsigned short uvbc[V * 512];    // [row][m*128+h] (L0, then L1)
    __shared__ unsigned short x1l[64 * X1LD];   // rows 0-39 x1; 48-59 relu(e0); rest 0
    __shared__ float gL[NSW * H];               // gates (L0, then L1)
    __shared__ float sA1l[NSW * H];
    __shared__ int   nbr[V][MAXD];
    __shared__ int   deg[V];

    int h = tid & 127, sub = tid >> 7;
    int lane = tid & 63, wv = tid >> 6;
    int lr = lane & 15, lk = lane >> 4;
    int n0w = wv * 64;

    // ---- phase 1: load x (bf16, padded), zero deg + x1l pad rows ----
    for (int o = tid; o < 48 * 32; o += 512) {
        int r = o >> 5, k = o & 31;
        float v = (r < V && k < FIN) ? x[(size_t)b * V * FIN + r * FIN + k] : 0.f;
        xb[r * 40 + k] = f2b(v);
    }
    if (tid < V) deg[tid] = 0;
    for (int o = tid; o < 12 * 128; o += 512) {
        int rr = o >> 7;
        int row = (rr < 8) ? 40 + rr : 60 + (rr - 8);
        x1l[row * X1LD + (o & 127)] = 0;
    }
    __syncthreads();

    // ---- phase 2: adjacency build + proj0 MFMA -> uvbc(L0) ----
    if (tid < NE) {
        int i = ei[tid], j = ei[NE + tid];
        int p = atomicAdd(&deg[i], 1); if (p < MAXD) nbr[i][p] = j;
        int q = atomicAdd(&deg[j], 1); if (q < MAXD) nbr[j][q] = i;
    } else if (tid < NE + NSW) {
        int k = tid - NE;
        int i = si[k], j = si[NSW + k];
        int p = atomicAdd(&deg[i], 1); if (p < MAXD) nbr[i][p] = j | ((k + 1) << 8);
    }
    {
        f32x4 acc[3][4];
#pragma unroll
        for (int rf = 0; rf < 3; ++rf)
#pragma unroll
            for (int cf = 0; cf < 4; ++cf) acc[rf][cf] = (f32x4){0.f, 0.f, 0.f, 0.f};
        int kseg = lk * 8;
        bf16x8 a0 = *(const bf16x8*)&xb[lr * 40 + kseg];
        bf16x8 a1 = *(const bf16x8*)&xb[(16 + lr) * 40 + kseg];
        bf16x8 a2 = *(const bf16x8*)&xb[(32 + lr) * 40 + kseg];
#pragma unroll
        for (int cf = 0; cf < 4; ++cf) {
            bf16x8 bf = *(const bf16x8*)&W0t[(n0w + cf * 16 + lr) * 32 + kseg];
            acc[0][cf] = __builtin_amdgcn_mfma_f32_16x16x32_bf16(a0, bf, acc[0][cf], 0, 0, 0);
            acc[1][cf] = __builtin_amdgcn_mfma_f32_16x16x32_bf16(a1, bf, acc[1][cf], 0, 0, 0);
            acc[2][cf] = __builtin_amdgcn_mfma_f32_16x16x32_bf16(a2, bf, acc[2][cf], 0, 0, 0);
        }
#pragma unroll
        for (int rf = 0; rf < 3; ++rf)
#pragma unroll
            for (int cf = 0; cf < 4; ++cf)
#pragma unroll
                for (int r = 0; r < 4; ++r) {
                    int row = rf * 16 + lk * 4 + r;
                    if (row < V) uvbc[row * 512 + n0w + cf * 16 + lr] = f2b(acc[rf][cf][r]);
                }
    }
    __syncthreads();

    // ---- phase 3: layer-0 gates -> gL; relu(e0) -> x1l rows 48..59 ----
    {
        float sA0 = 0.f;
#pragma unroll
        for (int f = 0; f < FIN; ++f) sA0 += embed[FIN + f] * WA0[f * H + h];
        for (int k = sub; k < NSW; k += 4) {
            int i = si[k], j = si[NSW + k];
            float e0 = sA0 + b2f(uvbc[i * 512 + 256 + h]) + b2f(uvbc[j * 512 + 384 + h]);
            gL[k * H + h] = sigmoidf(e0);
            x1l[(48 + k) * X1LD + h] = f2b(fmaxf(e0, 0.f));
        }
    }
    __syncthreads();

    // ---- phase 4: x1 via adjacency -> x1l rows 0..39 ----
    for (int i = sub * 10; i < sub * 10 + 10; ++i) {
        float acc = b2f(uvbc[i * 512 + h]);          // Ux
        int d = deg[i]; if (d > MAXD) d = MAXD;
        for (int p = 0; p < d; ++p) {
            int ent = nbr[i][p];
            float vv = b2f(uvbc[(ent & 255) * 512 + 128 + h]);   // Vx[j]
            int g = ent >> 8;
            if (g) vv *= gL[(g - 1) * H + h];
            acc += vv;
        }
        x1l[i * X1LD + h] = f2b(fmaxf(acc, 0.f));    // layer 0: no residual
    }
    __syncthreads();

    // ---- phase 5: proj1 + sA1 MFMA -> uvbc(L1), sA1l ----
    {
        f32x4 acc[3][4], accs = (f32x4){0.f, 0.f, 0.f, 0.f};
#pragma unroll
        for (int rf = 0; rf < 3; ++rf)
#pragma unroll
            for (int cf = 0; cf < 4; ++cf) acc[rf][cf] = (f32x4){0.f, 0.f, 0.f, 0.f};
#pragma unroll
        for (int kk = 0; kk < 4; ++kk) {
            int kseg = kk * 32 + lk * 8;
            bf16x8 a0 = *(const bf16x8*)&x1l[lr * X1LD + kseg];
            bf16x8 a1 = *(const bf16x8*)&x1l[(16 + lr) * X1LD + kseg];
            bf16x8 a2 = *(const bf16x8*)&x1l[(32 + lr) * X1LD + kseg];
            bf16x8 as = *(const bf16x8*)&x1l[(48 + lr) * X1LD + kseg];
#pragma unroll
            for (int cf = 0; cf < 4; ++cf) {
                bf16x8 bf = *(const bf16x8*)&Wt640[(size_t)(n0w + cf * 16 + lr) * H + kseg];
                acc[0][cf] = __builtin_amdgcn_mfma_f32_16x16x32_bf16(a0, bf, acc[0][cf], 0, 0, 0);
                acc[1][cf] = __builtin_amdgcn_mfma_f32_16x16x32_bf16(a1, bf, acc[1][cf], 0, 0, 0);
                acc[2][cf] = __builtin_amdgcn_mfma_f32_16x16x32_bf16(a2, bf, acc[2][cf], 0, 0, 0);
            }
            bf16x8 bs = *(const bf16x8*)&Wt640[(size_t)(512 + wv * 16 + lr) * H + kseg];
            accs = __builtin_amdgcn_mfma_f32_16x16x32_bf16(as, bs, accs, 0, 0, 0);
        }
#pragma unroll
        for (int rf = 0; rf < 3; ++rf)
#pragma unroll
            for (int cf = 0; cf < 4; ++cf)
#pragma unroll
                for (int r = 0; r < 4; ++r) {
                    int row = rf * 16 + lk * 4 + r;
                    if (row < V) uvbc[row * 512 + n0w + cf * 16 + lr] = f2b(acc[rf][cf][r]);
                }
#pragma unroll
        for (int r = 0; r < 4; ++r) {
            int sr = lk * 4 + r;
            if (sr < NSW) sA1l[sr * H + wv * 16 + lr] = accs[r];
        }
    }
    __syncthreads();

    // ---- phase 6: layer-1 gates -> gL; s2 switch rows -> Abf ----
    for (int k = sub; k < NSW; k += 4) {
        int i = si[k], j = si[NSW + k];
        float e1 = sA1l[k * H + h] + b2f(uvbc[i * 512 + 256 + h]) + b2f(uvbc[j * 512 + 384 + h]);
        gL[k * H + h] = sigmoidf(e1);
        float s1 = b2f(x1l[(48 + k) * X1LD + h]);
        Abf[(size_t)b * MLP_IN + k * H + h] = f2b(s1 + fmaxf(e1, 0.f));
    }
    __syncthreads();

    // ---- phase 7: x2 via adjacency (residual) -> Abf ----
    for (int i = sub * 10; i < sub * 10 + 10; ++i) {
        float acc = b2f(uvbc[i * 512 + h]);
        int d = deg[i]; if (d > MAXD) d = MAXD;
        for (int p = 0; p < d; ++p) {
            int ent = nbr[i][p];
            float vv = b2f(uvbc[(ent & 255) * 512 + 128 + h]);
            int g = ent >> 8;
            if (g) vv *= gL[(g - 1) * H + h];
            acc += vv;
        }
        float x2 = b2f(x1l[i * X1LD + h]) + fmaxf(acc, 0.f);
        Abf[(size_t)b * MLP_IN + NSW * H + i * H + h] = f2b(x2);
    }
}

// ---------------- MLP GEMM: fused W1 transpose+convert [r7 structure, finer split-K] ----------------
// partial[z][m][n] = Abf[m][k-chunk] @ W1[k-chunk][n]; grid(16,4,NCH=26) = 1664 blocks.
// block tile 64 rows x 64 cols; wave tile 32x32 (2x2 frags); NK=8 (K=256 per chunk).
__global__ __launch_bounds__(256) void k_mlp(const unsigned short* __restrict__ A,
        const float* __restrict__ W1, float* __restrict__ partial) {
    const int NK = 8;
    int tid = threadIdx.x;
    int lane = tid & 63, wvv = tid >> 6;
    int wr = (wvv >> 1) * 32, wc = (wvv & 1) * 32;
    int n0 = blockIdx.x * 64, m0 = blockIdx.y * 64;
    int kbase = blockIdx.z * NK * 32;

    __shared__ __align__(16) unsigned short a_lds[64 * 40];
    __shared__ __align__(16) unsigned short b_lds[64 * 40];

    f32x4 acc00 = {0,0,0,0}, acc01 = {0,0,0,0}, acc10 = {0,0,0,0}, acc11 = {0,0,0,0};

    int srow = tid >> 2, sseg = tid & 3;
    const int4* gA = (const int4*)(A + (size_t)(m0 + srow) * MLP_IN + kbase + sseg * 8);
    int lwsA = srow * 40 + sseg * 8;

    int bcol = tid & 63, bkg = tid >> 6;
    const float* gW = W1 + (size_t)(kbase + bkg * 8) * MLP_HID + n0 + bcol;
    int lwsB = bcol * 40 + bkg * 8;

    int a_off = (wr + (lane & 15)) * 40 + (lane >> 4) * 8;
    int b_off = (wc + (lane & 15)) * 40 + (lane >> 4) * 8;

    int4 ra = gA[0];
    float rfv[8];
#pragma unroll
    for (int i = 0; i < 8; ++i) rfv[i] = gW[(size_t)i * MLP_HID];

    for (int kk = 0; kk < NK; ++kk) {
        *(int4*)&a_lds[lwsA] = ra;
        {
            union { unsigned short us[8]; int4 v; } pk;
#pragma unroll
            for (int i = 0; i < 8; ++i) pk.us[i] = f2b(rfv[i]);
            *(int4*)&b_lds[lwsB] = pk.v;
        }
        __syncthreads();
        if (kk + 1 < NK) {
            ra = gA[(kk + 1) * 4];
            const float* g2 = gW + (size_t)(kk + 1) * 32 * MLP_HID;
#pragma unroll
            for (int i = 0; i < 8; ++i) rfv[i] = g2[(size_t)i * MLP_HID];
        }
        bf16x8 a0 = *(const bf16x8*)&a_lds[a_off];
        bf16x8 a1 = *(const bf16x8*)&a_lds[a_off + 16 * 40];
        bf16x8 b0 = *(const bf16x8*)&b_lds[b_off];
        bf16x8 b1 = *(const bf16x8*)&b_lds[b_off + 16 * 40];
        acc00 = __builtin_amdgcn_mfma_f32_16x16x32_bf16(a0, b0, acc00, 0, 0, 0);
        acc01 = __builtin_amdgcn_mfma_f32_16x16x32_bf16(a0, b1, acc01, 0, 0, 0);
        acc10 = __builtin_amdgcn_mfma_f32_16x16x32_bf16(a1, b0, acc10, 0, 0, 0);
        acc11 = __builtin_amdgcn_mfma_f32_16x16x32_bf16(a1, b1, acc11, 0, 0, 0);
        __syncthreads();
    }

    int crow = (lane >> 4) * 4, ccol = lane & 15;
    int row0 = m0 + wr + crow, row1 = row0 + 16;
    int col0 = n0 + wc + ccol, col1 = col0 + 16;
    float* dst = partial + (size_t)blockIdx.z * 256 * MLP_HID;
#pragma unroll
    for (int r = 0; r < 4; ++r) {
        dst[(size_t)(row0 + r) * MLP_HID + col0] = acc00[r];
        dst[(size_t)(row0 + r) * MLP_HID + col1] = acc01[r];
        dst[(size_t)(row1 + r) * MLP_HID + col0] = acc10[r];
        dst[(size_t)(row1 + r) * MLP_HID + col1] = acc11[r];
    }
}

// ---------------- generic bf16 MFMA GEMM (head): f32 split-K partial out ----------------
template<int MODE>
__global__ __launch_bounds__(256) void k_gemm(const unsigned short* __restrict__ A,
        const unsigned short* __restrict__ Bt, void* __restrict__ Cout,
        int K, int nk, int ldc) {
    int tid = threadIdx.x;
    int lane = tid & 63, wv = tid >> 6;
    int wr = (wv >> 1) * 32, wc = (wv & 1) * 32;
    int n0 = blockIdx.x * 64, m0 = blockIdx.y * 64;
    size_t kbase = (size_t)blockIdx.z * nk * 32;

    __shared__ __align__(16) unsigned short a_lds[64 * 40];
    __shared__ __align__(16) unsigned short b_lds[64 * 40];

    f32x4 acc00 = {0,0,0,0}, acc01 = {0,0,0,0}, acc10 = {0,0,0,0}, acc11 = {0,0,0,0};

    int srow = tid >> 2, sseg = tid & 3;
    const int4* gA = (const int4*)(A + (size_t)(m0 + srow) * K + kbase + sseg * 8);
    const int4* gB = (const int4*)(Bt + (size_t)(n0 + srow) * K + kbase + sseg * 8);
    int lws = srow * 40 + sseg * 8;

    int a_off = (wr + (lane & 15)) * 40 + (lane >> 4) * 8;
    int b_off = (wc + (lane & 15)) * 40 + (lane >> 4) * 8;

    int4 ra = gA[0], rb = gB[0];
    for (int kk = 0; kk < nk; ++kk) {
        *(int4*)&a_lds[lws] = ra;
        *(int4*)&b_lds[lws] = rb;
        __syncthreads();
        if (kk + 1 < nk) { ra = gA[(kk + 1) * 4]; rb = gB[(kk + 1) * 4]; }
        bf16x8 a0 = *(const bf16x8*)&a_lds[a_off];
        bf16x8 a1 = *(const bf16x8*)&a_lds[a_off + 16 * 40];
        bf16x8 b0 = *(const bf16x8*)&b_lds[b_off];
        bf16x8 b1 = *(const bf16x8*)&b_lds[b_off + 16 * 40];
        acc00 = __builtin_amdgcn_mfma_f32_16x16x32_bf16(a0, b0, acc00, 0, 0, 0);
        acc01 = __builtin_amdgcn_mfma_f32_16x16x32_bf16(a0, b1, acc01, 0, 0, 0);
        acc10 = __builtin_amdgcn_mfma_f32_16x16x32_bf16(a1, b0, acc10, 0, 0, 0);
        acc11 = __builtin_amdgcn_mfma_f32_16x16x32_bf16(a1, b1, acc11, 0, 0, 0);
        __syncthreads();
    }

    int crow = (lane >> 4) * 4, ccol = lane & 15;
    int row0 = m0 + wr + crow, row1 = row0 + 16;
    int col0 = n0 + wc + ccol, col1 = col0 + 16;
    float* dst = (float*)Cout + (size_t)blockIdx.z * (gridDim.y * 64) * ldc;
#pragma unroll
    for (int r = 0; r < 4; ++r) {
        dst[(size_t)(row0 + r) * ldc + col0] = acc00[r];
        dst[(size_t)(row0 + r) * ldc + col1] = acc01[r];
        dst[(size_t)(row1 + r) * ldc + col0] = acc10[r];
        dst[(size_t)(row1 + r) * ldc + col1] = acc11[r];
    }
}

// reduce MLP split-K partials + bias + relu -> bf16 hidden
__global__ void k_mred(const float* __restrict__ partial, const float* __restrict__ b1,
                       unsigned short* __restrict__ hiddenb) {
    int i = blockIdx.x * 256 + threadIdx.x;   // < 256*1024
    float s = b1[i & (MLP_HID - 1)];
#pragma unroll
    for (int z = 0; z < NCH; ++z) s += partial[(size_t)z * 256 * MLP_HID + i];
    hiddenb[i] = f2b(fmaxf(s, 0.f));
}

// ---------------- finalize: reduce head partials + postprocess ----------------
__global__ __launch_bounds__(128) void k_fin(const float* __restrict__ partial2,
        const float* __restrict__ b2, const float* __restrict__ A,
        const float* __restrict__ x_mod, float* __restrict__ outp) {
    int b = blockIdx.x;
    int tid = threadIdx.x;
    __shared__ float o[OUTD];
    __shared__ float gt[M], vv[V], pfc[M], qfc[M];

    if (tid < OUTD) {
        float s = b2[tid];
#pragma unroll
        for (int z = 0; z < 4; ++z) s += partial2[(size_t)z * 256 * 128 + b * 128 + tid];
        o[tid] = s;
    }
    __syncthreads();

    if (tid < M) {
        float g = (tid < M - NSW) ? 1.0f : sigmoidf(o[M + V + (tid - (M - NSW))]);
        gt[tid] = g;
        pfc[tid] = g * o[tid];
    }
    if (tid < V) vv[tid] = (tid == 0) ? 1.0f : o[M + tid];
    __syncthreads();

    if (tid < M) {
        float acc = 0.f;
        for (int x = 0; x < V; ++x) acc += vv[x] * A[x * M + tid];
        qfc[tid] = gt[tid] * acc;
    }
    __syncthreads();

    float* zb = outp + (size_t)b * ZDIM;
    if (tid < M) zb[tid] = pfc[tid];
    if (tid < V) zb[M + tid] = vv[tid];
    if (tid < M) zb[M + V + tid] = gt[tid];

    float* zcb = outp + (size_t)B * ZDIM + (size_t)b * ZCDIM;
    if (tid < M) zcb[tid] = qfc[tid];
    if (tid < V) {
        float accp = 0.f, accq = 0.f;
        for (int m = 0; m < M; ++m) {
            float a = A[tid * M + m];
            accp += a * pfc[m];
            accq += a * qfc[m];
        }
        zcb[M + tid]     = x_mod[(size_t)(b * V + tid) * FIN + 0] + accp;
        zcb[M + V + tid] = x_mod[(size_t)(b * V + tid) * FIN + 1] + accq;
    }
}

extern "C" void kernel_launch(void* const* d_in, const int* in_sizes, int n_in,
                              void* d_out, int out_size, void* d_ws, size_t ws_size,
                              hipStream_t stream) {
    const float* x_mod = (const float*)d_in[0];
    const int*   ei    = (const int*)d_in[1];
    const int*   si    = (const int*)d_in[2];
    const float* A     = (const float*)d_in[3];
    const float* embed = (const float*)d_in[4];
    const float* WU0   = (const float*)d_in[5];
    const float* WV0   = (const float*)d_in[6];
    const float* WA0   = (const float*)d_in[7];
    const float* WB0   = (const float*)d_in[8];
    const float* WC0   = (const float*)d_in[9];
    const float* WU1   = (const float*)d_in[10];
    const float* WV1   = (const float*)d_in[11];
    const float* WA1   = (const float*)d_in[12];
    const float* WB1   = (const float*)d_in[13];
    const float* WC1   = (const float*)d_in[14];
    const float* W1    = (const float*)d_in[15];
    const float* b1    = (const float*)d_in[16];
    const float* W2    = (const float*)d_in[17];
    const float* b2    = (const float*)d_in[18];
    float* out = (float*)d_out;

    // Workspace layout (byte offsets), ~32 MB
    char* ws = (char*)d_ws;
    unsigned short* W0t      = (unsigned short*)(ws + 0);          //    32,768
    unsigned short* Wt640    = (unsigned short*)(ws + 32768);      //   163,840
    unsigned short* W2t      = (unsigned short*)(ws + 196608);     //   262,144
    unsigned short* Abf      = (unsigned short*)(ws + 458752);     // 3,407,872 (rows >=200 stale, benign)
    float*          partialM = (float*)(ws + 3866624);             // 27,262,976 (26 chunks)
    unsigned short* hiddenb  = (unsigned short*)(ws + 31129600);   //   524,288
    float*          partial2 = (float*)(ws + 31653888);            //   524,288

    // 1. small weight prep (W0t, Wt640, W2t)
    k_prep<<<112, 256, 0, stream>>>(WU0, WV0, WB0, WC0, WU1, WV1, WB1, WC1, WA1, W2,
                                    W0t, Wt640, W2t);
    // 2. fully fused GNN (both layers, MFMA projections) -> Abf
    k_gnn<<<B, 512, 0, stream>>>(x_mod, ei, si, embed, WA0, W0t, Wt640, Abf);
    // 3. MLP hidden: (256x6656) @ W1 (f32, on-the-fly transpose), split-K=26
    //    1664 blocks = 26 waves/CU (r7/r9/r10 dose-response: occupancy is the lever)
    k_mlp<<<dim3(16, 4, NCH), 256, 0, stream>>>(Abf, W1, partialM);
    // 4. reduce + bias + relu -> hiddenb bf16
    k_mred<<<256 * MLP_HID / 256, 256, 0, stream>>>(partialM, b1, hiddenb);
    // 5. head GEMM: (256x1024) @ (1024x128), split-K=4 -> partial2
    k_gemm<2><<<dim3(2, 4, 4), 256, 0, stream>>>(hiddenb, W2t, partial2, MLP_HID, 8, 128);
    // 6. finalize: reduce + graph postprocess
    k_fin<<<B, 128, 0, stream>>>(partial2, b2, A, x_mod, out);
}